// Round 10
// baseline (377.964 us; speedup 1.0000x reference)
//
#include <hip/hip_runtime.h>
#include <math.h>

#define Dm 1024
#define Hh 16
#define DHd 64
#define Ff 4096
#define Tt 2048
#define Bb 2

#define ATT_C2 0.18033688011112042f   // 0.125 * log2(e), folded into Q at QK GEMM

typedef __bf16 bf16_8 __attribute__((ext_vector_type(8)));
typedef __bf16 bf16x2 __attribute__((ext_vector_type(2)));
typedef __bf16 bf16x4 __attribute__((ext_vector_type(4)));
typedef float  f32x4  __attribute__((ext_vector_type(4)));
typedef float  f32x16 __attribute__((ext_vector_type(16)));
typedef unsigned int u32x4 __attribute__((ext_vector_type(4)));
typedef unsigned int u32x8s __attribute__((ext_vector_type(8)));

__device__ __forceinline__ unsigned short f2bf(float f) {
    unsigned int u = __float_as_uint(f);
    unsigned int r = (u + 0x7fffu + ((u >> 16) & 1u)) >> 16;   // RNE
    return (unsigned short)r;
}

// native packed f32->bf16 (gfx950 v_cvt_pk_bf16_f32), RNE — fallback to cast
__device__ __forceinline__ bf16x2 pkbf(float a, float b) {
#if __has_builtin(__builtin_amdgcn_cvt_pk_bf16_f32)
    return __builtin_amdgcn_cvt_pk_bf16_f32(a, b);
#else
    bf16x2 r; r[0] = (__bf16)a; r[1] = (__bf16)b; return r;
#endif
}
__device__ __forceinline__ bf16x4 pkbf4(float a, float b, float c, float d) {
    bf16x2 lo = pkbf(a, b), hi = pkbf(c, d);
    return __builtin_shufflevector(lo, hi, 0, 1, 2, 3);
}

// v_permlane32_swap_b32: for lane l<32: a'=a[l], b'=a[l+32]; l>=32: a'=b[l-32], b'=b[l].
__device__ __forceinline__ void plswap32(unsigned &a, unsigned &b) {
#if __has_builtin(__builtin_amdgcn_permlane32_swap)
    auto r = __builtin_amdgcn_permlane32_swap((int)a, (int)b, false, false);
    a = (unsigned)r[0]; b = (unsigned)r[1];
#else
    asm volatile("v_permlane32_swap_b32 %0, %1" : "+v"(a), "+v"(b));
#endif
}

__device__ __forceinline__ void gld_lds16(const void* g, void* l) {
    __builtin_amdgcn_global_load_lds(
        (const __attribute__((address_space(1))) void*)g,
        (__attribute__((address_space(3))) void*)l,
        16, 0, 0);
}

// 32 consecutive u32 via scalar loads (off the VALU pipe). p must be
// wave-uniform. Outputs EARLY-CLOBBER ("=&s") so the allocator cannot
// overlap the input address pair with an output tuple (round-4 lesson).
__device__ __forceinline__ void sload32(const unsigned* p,
        u32x8s &a, u32x8s &b, u32x8s &c, u32x8s &d) {
    asm volatile(
        "s_load_dwordx8 %0, %4, 0x0\n\t"
        "s_load_dwordx8 %1, %4, 0x20\n\t"
        "s_load_dwordx8 %2, %4, 0x40\n\t"
        "s_load_dwordx8 %3, %4, 0x60\n\t"
        "s_waitcnt lgkmcnt(0)"
        : "=&s"(a), "=&s"(b), "=&s"(c), "=&s"(d)
        : "s"(p));
}

// select e where keep-bit set, else 0: one VALU op, mask from SGPR pair
__device__ __forceinline__ float selkeep(float e, unsigned long long keep) {
    float r;
    asm("v_cndmask_b32 %0, 0, %1, %2" : "=v"(r) : "v"(e), "s"(keep));
    return r;
}

// ---------------------------------------------------------------------------
// One-shot preprocess: all fp32->bf16 weight/src conversions + mask bit-pack
// (t-transposed, keep-inverted) + QK bias concat, in a single dispatch.
// ---------------------------------------------------------------------------
__global__ __launch_bounds__(256) void preprocess_kernel(
    const float* __restrict__ q_w, const float* __restrict__ k_w,
    const float* __restrict__ v_w, const float* __restrict__ o_w,
    const float* __restrict__ l1_w, const float* __restrict__ l2_w,
    const float* __restrict__ src, const int* __restrict__ mask,
    const float* __restrict__ q_b, const float* __restrict__ k_b,
    unsigned short* __restrict__ qkw, unsigned short* __restrict__ vw16,
    unsigned short* __restrict__ ow,  unsigned short* __restrict__ l1w,
    unsigned short* __restrict__ l2w, unsigned short* __restrict__ srcb,
    unsigned* __restrict__ mbT, float* __restrict__ qkb)
{
    const int bid = blockIdx.x;
    const int tid = threadIdx.x;
    if (bid < 16384) {                      // fp32 -> bf16, float4 granules
        int i = bid * 256 + tid;
        const float* sp; unsigned short* dp; int off;
        if (i < 1048576) {
            if (i < 262144)      { sp = q_w; dp = qkw;           off = i; }
            else if (i < 524288) { sp = k_w; dp = qkw + 1048576; off = i - 262144; }
            else if (i < 786432) { sp = v_w; dp = vw16;          off = i - 524288; }
            else                 { sp = o_w; dp = ow;            off = i - 786432; }
        } else if (i < 2097152)  { sp = l1_w; dp = l1w;          off = i - 1048576; }
        else if (i < 3145728)    { sp = l2_w; dp = l2w;          off = i - 2097152; }
        else                     { sp = src;  dp = srcb;         off = i - 3145728; }
        float4 v = ((const float4*)sp)[off];
        ((bf16x4*)dp)[off] = pkbf4(v.x, v.y, v.z, v.w);
    } else if (bid < 16896) {
        // mask [2048 t][2048 s] -> mbT[64][2048]: bit j of [tw32][s] =
        // KEEP (mask==0) for t = tw32*32+j. 131072 words, 1/thread.
        int w = (bid - 16384) * 256 + tid;
        int tw32 = w >> 11, s = w & 2047;
        const int* p = mask + (size_t)(tw32 * 32) * 2048 + s;
        unsigned bits = 0;
        #pragma unroll
        for (int j = 0; j < 32; ++j)
            bits |= (p[(size_t)j * 2048] == 0 ? 1u : 0u) << j;
        mbT[w] = bits;
    } else {                                // QK bias concat (2048)
        int i = (bid - 16896) * 256 + tid;
        qkb[i] = (i < 1024) ? q_b[i] : k_b[i - 1024];
    }
}

// ---------------------------------------------------------------------------
// Split-K GEMM with IN-BLOCK split-K over 8 waves. 128x128 tile, BK=128
// staged (64 KB LDS); waves 0-3 consume K-cols [0,64), waves 4-7 [64,128)
// -> 16 waves/CU (4/SIMD). kh=1 partials combined into kh=0 through the
// dead staging LDS. fp32 out; z=0 -> C (+bias), z=1 -> C2.
// XCD remap (kept — round-9 net win on these BW-pressured instances).
// Round-7 lesson: never raise min-waves past 4 (VGPR<=64 spills accs).
// ---------------------------------------------------------------------------
__global__ __launch_bounds__(512, 4) void gemm_splitk8_kernel(
    const unsigned short* __restrict__ A, const unsigned short* __restrict__ W,
    const float* __restrict__ bias, float* __restrict__ C, float* __restrict__ C2,
    int K, int ldc, int ksub)
{
    __shared__ __align__(16) char smem[65536];
    __bf16* As = (__bf16*)smem;              // [128][128] 32 KB
    __bf16* Bs = (__bf16*)(smem + 32768);    // [128][128] 32 KB

    const int tid  = threadIdx.x;
    const int lane = tid & 63;
    const int wave = tid >> 6;               // 0..7
    const int wvu  = __builtin_amdgcn_readfirstlane(wave);
    const int wq   = wvu & 3;                // output sub-tile
    const int kh   = wvu >> 2;               // K-half of the staged 128 cols
    // ---- XCD remap: xcd = blockIdx.x (flat%8 on 8-wide grid) ----
    const int xcd = blockIdx.x;              // 0..7
    const int ib  = blockIdx.y;              // 0..31
    const int mq  = (xcd >> 1) * 8 + (ib & 7);    // 0..31
    const int nq  = (xcd & 1) * 4 + (ib >> 3);    // 0..7
    const int m0 = mq * 128;
    const int n0 = nq * 128;
    const int wm = (wq & 1) * 64;
    const int wn = (wq >> 1) * 64;
    const int quad = lane >> 4;
    const int lm = lane & 15;
    const int z  = blockIdx.z;
    const int kstart = z * ksub;
    float* Cz = (z == 0) ? C : C2;

    const int lr4 = lane >> 4;
    const int lc  = lane & 15;

    f32x4 acc[4][4];
    #pragma unroll
    for (int i = 0; i < 4; i++)
        #pragma unroll
        for (int j = 0; j < 4; j++) {
            acc[i][j][0] = 0.f; acc[i][j][1] = 0.f;
            acc[i][j][2] = 0.f; acc[i][j][3] = 0.f;
        }

    for (int k0 = kstart; k0 < kstart + ksub; k0 += 128) {
        __syncthreads();
        #pragma unroll
        for (int i = 0; i < 4; ++i) {
            int seg = wave * 4 + i;          // 0..31, 4 rows each
            int r = seg * 4 + lr4;           // 0..127
            int ch = lc ^ (r & 7);           // global chunk for swizzled LDS
            gld_lds16(A + (size_t)(m0 + r) * K + k0 + ch * 8, &As[seg * 512]);
            gld_lds16(W + (size_t)(n0 + r) * K + k0 + ch * 8, &Bs[seg * 512]);
        }
        __syncthreads();
        #pragma unroll
        for (int kk = 0; kk < 2; ++kk) {
            bf16_8 af[4], bfr[4];
            #pragma unroll
            for (int t = 0; t < 4; ++t) {
                int ra = wm + t * 16 + lm;
                int ca = (kh * 8 + kk * 4 + quad) ^ (ra & 7);
                af[t]  = *(const bf16_8*)&As[ra * 128 + ca * 8];
                int rb = wn + t * 16 + lm;
                int cb = (kh * 8 + kk * 4 + quad) ^ (rb & 7);
                bfr[t] = *(const bf16_8*)&Bs[rb * 128 + cb * 8];
            }
            #pragma unroll
            for (int i = 0; i < 4; i++)
                #pragma unroll
                for (int j = 0; j < 4; j++)
                    acc[i][j] = __builtin_amdgcn_mfma_f32_16x16x32_bf16(
                        af[i], bfr[j], acc[i][j], 0, 0, 0);
        }
    }

    // ---- combine kh=1 -> kh=0 through the (dead) staging LDS ----
    __syncthreads();
    float* comb = (float*)smem;
    if (kh == 1) {
        #pragma unroll
        for (int i = 0; i < 4; i++)
            #pragma unroll
            for (int j = 0; j < 4; j++)
                *(f32x4*)&comb[wq * 4096 + (i * 4 + j) * 256 + lane * 4] =
                    acc[i][j];
    }
    __syncthreads();
    if (kh == 0) {
        float bvc[4];
        #pragma unroll
        for (int j = 0; j < 4; j++)
            bvc[j] = (z == 0) ? bias[n0 + wn + j * 16 + lm] : 0.f;
        #pragma unroll
        for (int i = 0; i < 4; i++)
            #pragma unroll
            for (int j = 0; j < 4; j++) {
                f32x4 v4 = *(const f32x4*)&comb[
                    wq * 4096 + (i * 4 + j) * 256 + lane * 4];
                int col = n0 + wn + j * 16 + lm;
                #pragma unroll
                for (int r = 0; r < 4; r++) {
                    int row = m0 + wm + i * 16 + quad * 4 + r;
                    Cz[(size_t)row * ldc + col] = acc[i][j][r] + v4[r] + bvc[j];
                }
            }
    }
}

// ---------------------------------------------------------------------------
// Merged QK + Vt GEMM v2: 8-wave in-block split-K (round-10).
// Round-9 post-mortem: old 4-wave qkvt was latency-bound (MfmaUtil 16,
// VALU 24, occ 17, HBM 11%); the QK XCD remap REGRESSED it +10us (fetch
// halved but concurrent blocks stopped sharing A-panels in time) -> remap
// reverted to identity, structure converted to the proven splitk8 form:
// 512 thr, BK=128, 64 KB LDS, kh=wave>>2 K-halves, LDS combine, 16 waves/CU.
// blocks [0,512):   qk16[4096,2048] = srcb @ [q_w;k_w]^T + qkb, Q cols xC2
// blocks [512,768): vtf [1024,4096] = vw16 @ srcb^T + v_b (row bias)
// ---------------------------------------------------------------------------
__global__ __launch_bounds__(512, 4) void gemm_qkvt8_kernel(
    const unsigned short* __restrict__ srcb, const unsigned short* __restrict__ qkw,
    const unsigned short* __restrict__ vw16, const float* __restrict__ qkb,
    const float* __restrict__ v_b,
    unsigned short* __restrict__ qk16, unsigned short* __restrict__ vtf)
{
    __shared__ __align__(16) char smem[65536];
    __bf16* As = (__bf16*)smem;              // [128][128] 32 KB
    __bf16* Bs = (__bf16*)(smem + 32768);    // [128][128] 32 KB

    const int bid = blockIdx.x;
    const unsigned short *A, *W;
    const float* bias;
    unsigned short* C;
    int m0, n0, ldc;
    bool qscale, rowbias;
    if (bid < 512) {
        A = srcb; W = qkw; bias = qkb; C = qk16;
        n0 = (bid & 15) * 128; m0 = (bid >> 4) * 128;   // identity (reverted)
        ldc = 2048; qscale = true; rowbias = false;
    } else {
        int b2 = bid - 512;
        A = vw16; W = srcb; bias = v_b; C = vtf;
        n0 = (b2 & 31) * 128; m0 = (b2 >> 5) * 128;
        ldc = 4096; qscale = false; rowbias = true;
    }

    const int tid  = threadIdx.x;
    const int lane = tid & 63;
    const int wave = tid >> 6;               // 0..7
    const int wvu  = __builtin_amdgcn_readfirstlane(wave);
    const int wq   = wvu & 3;
    const int kh   = wvu >> 2;
    const int wm = (wq & 1) * 64;
    const int wn = (wq >> 1) * 64;
    const int quad = lane >> 4;
    const int lm = lane & 15;
    const int lr4 = lane >> 4;
    const int lc  = lane & 15;

    f32x4 acc[4][4];
    #pragma unroll
    for (int i = 0; i < 4; i++)
        #pragma unroll
        for (int j = 0; j < 4; j++) {
            acc[i][j][0] = 0.f; acc[i][j][1] = 0.f;
            acc[i][j][2] = 0.f; acc[i][j][3] = 0.f;
        }

    for (int k0 = 0; k0 < 1024; k0 += 128) {
        __syncthreads();
        #pragma unroll
        for (int i = 0; i < 4; ++i) {
            int seg = wave * 4 + i;          // 0..31, 4 rows each
            int r = seg * 4 + lr4;           // 0..127
            int ch = lc ^ (r & 7);
            gld_lds16(A + (size_t)(m0 + r) * 1024 + k0 + ch * 8, &As[seg * 512]);
            gld_lds16(W + (size_t)(n0 + r) * 1024 + k0 + ch * 8, &Bs[seg * 512]);
        }
        __syncthreads();
        #pragma unroll
        for (int kk = 0; kk < 2; ++kk) {
            bf16_8 af[4], bfr[4];
            #pragma unroll
            for (int t = 0; t < 4; ++t) {
                int ra = wm + t * 16 + lm;
                int ca = (kh * 8 + kk * 4 + quad) ^ (ra & 7);
                af[t]  = *(const bf16_8*)&As[ra * 128 + ca * 8];
                int rb = wn + t * 16 + lm;
                int cb = (kh * 8 + kk * 4 + quad) ^ (rb & 7);
                bfr[t] = *(const bf16_8*)&Bs[rb * 128 + cb * 8];
            }
            #pragma unroll
            for (int i = 0; i < 4; i++)
                #pragma unroll
                for (int j = 0; j < 4; j++)
                    acc[i][j] = __builtin_amdgcn_mfma_f32_16x16x32_bf16(
                        af[i], bfr[j], acc[i][j], 0, 0, 0);
        }
    }

    // ---- combine kh=1 -> kh=0 through the (dead) staging LDS ----
    __syncthreads();
    float* comb = (float*)smem;
    if (kh == 1) {
        #pragma unroll
        for (int i = 0; i < 4; i++)
            #pragma unroll
            for (int j = 0; j < 4; j++)
                *(f32x4*)&comb[wq * 4096 + (i * 4 + j) * 256 + lane * 4] =
                    acc[i][j];
    }
    __syncthreads();
    if (kh == 0) {
        float bvc[4];
        float brr[4][4];
        if (!rowbias) {
            #pragma unroll
            for (int j = 0; j < 4; j++) bvc[j] = bias[n0 + wn + j * 16 + lm];
        } else {
            #pragma unroll
            for (int i = 0; i < 4; i++) {
                float4 t4 = *(const float4*)&bias[m0 + wm + i * 16 + quad * 4];
                brr[i][0] = t4.x; brr[i][1] = t4.y;
                brr[i][2] = t4.z; brr[i][3] = t4.w;
            }
        }
        #pragma unroll
        for (int i = 0; i < 4; i++)
            #pragma unroll
            for (int j = 0; j < 4; j++) {
                f32x4 v4 = *(const f32x4*)&comb[
                    wq * 4096 + (i * 4 + j) * 256 + lane * 4];
                int col = n0 + wn + j * 16 + lm;
                #pragma unroll
                for (int r = 0; r < 4; r++) {
                    int row = m0 + wm + i * 16 + quad * 4 + r;
                    float v = acc[i][j][r] + v4[r] +
                              (rowbias ? brr[i][r] : bvc[j]);
                    if (qscale && col < 1024) v *= ATT_C2;
                    C[(size_t)row * ldc + col] = f2bf(v);
                }
            }
    }
}

// ---------------------------------------------------------------------------
// FFN1 GEMM: hb[4096,4096] = relu(x1b[4096,1024] @ l1w[4096,1024]^T + l1_b).
// 256x128 tile, BK=64, LDS 48 KB, acc 4x8 per wave. 512 blocks = 2/CU exact.
// XCD remap kept (round-9 net win).
// ---------------------------------------------------------------------------
__global__ __launch_bounds__(256, 2) void gemm_ffn1_kernel(
    const unsigned short* __restrict__ A, const unsigned short* __restrict__ W,
    const float* __restrict__ bias, unsigned short* __restrict__ C)
{
    __shared__ __bf16 As[256][64];   // 32 KB
    __shared__ __bf16 Bs[128][64];   // 16 KB
    const int tid  = threadIdx.x;
    const int lane = tid & 63;
    const int wave = tid >> 6;
    // ---- XCD remap ----
    const int f   = blockIdx.x + (blockIdx.y << 5);  // 0..511
    const int xcd = f & 7;
    const int ib  = f >> 3;                          // 0..63
    const int mq  = (xcd >> 1) * 4 + (ib & 3);       // 0..15
    const int nq  = (xcd & 1) * 16 + (ib >> 2);      // 0..31
    const int m0 = mq * 256;
    const int n0 = nq * 128;
    const int lr8 = lane >> 3;
    const int gch = (lane & 7) ^ lr8;
    const int quad = lane >> 4;
    const int lm = lane & 15;

    f32x4 acc[4][8];
    #pragma unroll
    for (int i = 0; i < 4; i++)
        #pragma unroll
        for (int j = 0; j < 8; j++) {
            acc[i][j][0] = 0.f; acc[i][j][1] = 0.f;
            acc[i][j][2] = 0.f; acc[i][j][3] = 0.f;
        }

    for (int k0 = 0; k0 < 1024; k0 += 64) {
        __syncthreads();
        #pragma unroll
        for (int i = 0; i < 8; i++) {          // A: 8 segments/wave
            int seg = wave * 8 + i;
            int r = seg * 8 + lr8;
            gld_lds16(A + (size_t)(m0 + r) * 1024 + k0 + gch * 8, &As[seg * 8][0]);
        }
        #pragma unroll
        for (int i = 0; i < 4; i++) {          // B: 4 segments/wave
            int seg = wave * 4 + i;
            int r = seg * 8 + lr8;
            gld_lds16(W + (size_t)(n0 + r) * 1024 + k0 + gch * 8, &Bs[seg * 8][0]);
        }
        __syncthreads();
        #pragma unroll
        for (int kh = 0; kh < 2; kh++) {
            const int ch = (kh * 4 + quad) ^ (lm & 7);
            bf16_8 af[4], bfr[8];
            #pragma unroll
            for (int t = 0; t < 4; t++)
                af[t] = *(const bf16_8*)&As[wave * 64 + t * 16 + lm][ch * 8];
            #pragma unroll
            for (int j = 0; j < 8; j++)
                bfr[j] = *(const bf16_8*)&Bs[j * 16 + lm][ch * 8];
            #pragma unroll
            for (int i = 0; i < 4; i++)
                #pragma unroll
                for (int j = 0; j < 8; j++)
                    acc[i][j] = __builtin_amdgcn_mfma_f32_16x16x32_bf16(
                        af[i], bfr[j], acc[i][j], 0, 0, 0);
        }
    }

    float bv[8];
    #pragma unroll
    for (int j = 0; j < 8; j++) bv[j] = bias[n0 + j * 16 + lm];

    #pragma unroll
    for (int i = 0; i < 4; i++)
        #pragma unroll
        for (int j = 0; j < 8; j++) {
            int col = n0 + j * 16 + lm;
            #pragma unroll
            for (int r = 0; r < 4; r++) {
                int row = m0 + wave * 64 + i * 16 + quad * 4 + r;
                float v = fmaxf(acc[i][j][r] + bv[j], 0.f);
                C[(size_t)row * Ff + col] = f2bf(v);
            }
        }
}

// ---------------------------------------------------------------------------
// MFMA flash attention v5b (proven 50.1us, 56 VGPR, 16 waves/CU).
// Round-8 A/B: s_setprio null -> removed. Round-7: never 8 waves/SIMD here.
// Wave pairs (wq, wq+4) share one 32-t range; sh=wave>>2 picks s-blocks
// {0,1} or {2,3} of each 128-s tile. O/l partial combine through LDS.
// 512 thr, K/V double-buffered 64 KB, grid (16,32) = 2 blk/CU.
// ---------------------------------------------------------------------------
__global__ __launch_bounds__(512, 4) void attn_mfma_kernel(
    const unsigned short* __restrict__ qk,
    const unsigned short* __restrict__ vt,
    const unsigned* __restrict__ mbT,
    unsigned short* __restrict__ out)
{
    __shared__ __align__(16) char smem[65536];
    __bf16* KsP = (__bf16*)smem;             // [2][8192] = 2 x 16 KB
    __bf16* VtP = (__bf16*)(smem + 32768);   // [2][8192] = 2 x 16 KB

    const int tid  = threadIdx.x;
    const int lane = tid & 63;
    const int wave = tid >> 6;           // 0..7
    const int l31  = lane & 31;
    const int hi   = lane >> 5;
    const int x7   = l31 & 7;
    const int bh = blockIdx.y;
    const int b = bh >> 4, h = bh & 15;
    // wave-uniform (SGPR) wave decomposition: wq = t-range, sh = s-half
    const int wvu = __builtin_amdgcn_readfirstlane(wave);
    const int wq  = wvu & 3;
    const int sh  = wvu >> 2;
    const int tw = blockIdx.x * 128 + wq * 32;
    const unsigned* mrow = mbT + (size_t)(blockIdx.x * 4 + wq) * 2048;

    // Q B-frags: B[k=hi*8+j][col=t=l31], 4 dsteps of 16 covering d=0..63
    bf16_8 qf[4];
    #pragma unroll
    for (int ds4 = 0; ds4 < 4; ++ds4)
        qf[ds4] = *(const bf16_8*)(qk +
            (size_t)(b * Tt + tw + l31) * 2048 + h * DHd + ds4 * 16 + hi * 8);

    f32x16 oacc[2];
    f32x16 ol;
    f32x16 z16;
    #pragma unroll
    for (int r = 0; r < 16; ++r) {
        oacc[0][r] = 0.f; oacc[1][r] = 0.f; ol[r] = 0.f; z16[r] = 0.f;
    }
    bf16_8 vone;
    {
        __bf16 one = (__bf16)1.0f;
        #pragma unroll
        for (int j = 0; j < 8; ++j) vone[j] = one;
    }

    const int krow8 = lane >> 3;
    const int kj    = (lane & 7) ^ krow8;    // K staging swizzle
    const int vr4   = lane >> 4;

    auto STAGE = [&](int nb, int s0) {
        #pragma unroll
        for (int i = 0; i < 2; ++i) {
            int ci = wave * 2 + i;           // 0..15
            {
                int r = 8 * ci + krow8;
                const unsigned short* g = qk +
                    (size_t)(b * Tt + s0 + r) * 2048 + 1024 + h * DHd + kj * 8;
                gld_lds16(g, &KsP[nb * 8192 + ci * 512]);
            }
            {
                int d = 4 * ci + vr4;
                int jj = (lane & 15) ^ (d & 7);
                const unsigned short* g = vt +
                    (size_t)(h * DHd + d) * 4096 + b * Tt + s0 + jj * 8;
                gld_lds16(g, &VtP[nb * 8192 + ci * 512]);
            }
        }
    };

    STAGE(0, 0);

    for (int st = 0; st < 16; ++st) {
        const int cb = st & 1;
        const int s0 = st * 128;
        __syncthreads();                     // buf[cb] staged; buf[cb^1] free

        if (st < 15) STAGE(cb ^ 1, s0 + 128);

        #pragma unroll
        for (int sbl = 0; sbl < 2; ++sbl) {
            const int sb = sh * 2 + sbl;     // this wave's s-block (uniform)
            // keep-bit words for s = s0+sb*32 .. +31 (scalar pipe)
            u32x8s ma, mbw, mc, md;
            sload32(mrow + s0 + sb * 32, ma, mbw, mc, md);

            // ---- S^T: 32 s x 32 t, K streamed from LDS, Q in regs ----
            f32x16 sacc = z16;
            #pragma unroll
            for (int ds4 = 0; ds4 < 4; ++ds4) {
                bf16_8 kf = *(const bf16_8*)&KsP[cb * 8192 +
                    (sb * 32 + l31) * 64 + (((ds4 * 2 + hi) ^ x7) * 8)];
                sacc = __builtin_amdgcn_mfma_f32_32x32x16_bf16(
                    kf, qf[ds4], sacc, 0, 0, 0);
            }
            // ---- exp2 + SGPR-mask select (1 cndmask/elem) ----
            float p[16];
            #pragma unroll
            for (int g = 0; g < 4; ++g) {
                u32x8s vv = (g == 0) ? ma : (g == 1) ? mbw : (g == 2) ? mc : md;
                #pragma unroll
                for (int m = 0; m < 4; ++m) {
                    const int reg = g * 4 + m;
                    unsigned long long keep =
                        ((unsigned long long)vv[m + 4] << 32) |
                        (unsigned long long)vv[m];
                    float e = __builtin_amdgcn_exp2f(sacc[reg]);
                    p[reg] = selkeep(e, keep);
                }
            }
            // ---- in-register repack to PV A-frags (T12) ----
            unsigned u[4], v[4];
            #pragma unroll
            for (int g = 0; g < 4; ++g) {
                u[g] = __builtin_bit_cast(unsigned, pkbf(p[g * 4 + 0], p[g * 4 + 1]));
                v[g] = __builtin_bit_cast(unsigned, pkbf(p[g * 4 + 2], p[g * 4 + 3]));
            }
            plswap32(u[0], u[1]); plswap32(v[0], v[1]);   // kstep0: s 0..15
            plswap32(u[2], u[3]); plswap32(v[2], v[3]);   // kstep1: s 16..31
            u32x4 w0; w0[0] = u[0]; w0[1] = v[0]; w0[2] = u[1]; w0[3] = v[1];
            u32x4 w1; w1[0] = u[2]; w1[1] = v[2]; w1[2] = u[3]; w1[3] = v[3];
            bf16_8 pa0 = __builtin_bit_cast(bf16_8, w0);
            bf16_8 pa1 = __builtin_bit_cast(bf16_8, w1);
            // ---- PV + l: O[t][d] += P V, l[t] += P·1 ----
            #pragma unroll
            for (int kst = 0; kst < 2; ++kst) {
                bf16_8 pa = kst ? pa1 : pa0;
                #pragma unroll
                for (int dblk = 0; dblk < 2; ++dblk) {
                    int cpos = (sb * 4 + kst * 2 + hi) ^ x7;
                    bf16_8 vf = *(const bf16_8*)&VtP[cb * 8192 +
                        ((dblk * 32 + l31) * 16 + cpos) * 8];
                    oacc[dblk] = __builtin_amdgcn_mfma_f32_32x32x16_bf16(
                        pa, vf, oacc[dblk], 0, 0, 0);
                }
                ol = __builtin_amdgcn_mfma_f32_32x32x16_bf16(
                    pa, vone, ol, 0, 0, 0);
            }
        }
    }

    // ---- combine wave-pair partials (sh=1 -> sh=0) through LDS ----
    // layout: comb[wq*3072 + piece*256 + lane*4], piece 0..7 = oacc, 8..11 = ol
    __syncthreads();                         // all compute done; K/V dead
    float* comb = (float*)smem;              // 48 KB of the 64 KB
    if (sh == 1) {
        #pragma unroll
        for (int dblk = 0; dblk < 2; ++dblk)
            #pragma unroll
            for (int q = 0; q < 4; ++q) {
                float4 v4 = { oacc[dblk][q * 4 + 0], oacc[dblk][q * 4 + 1],
                              oacc[dblk][q * 4 + 2], oacc[dblk][q * 4 + 3] };
                *(float4*)&comb[wq * 3072 + (dblk * 4 + q) * 256 + lane * 4] = v4;
            }
        #pragma unroll
        for (int q = 0; q < 4; ++q) {
            float4 v4 = { ol[q * 4 + 0], ol[q * 4 + 1],
                          ol[q * 4 + 2], ol[q * 4 + 3] };
            *(float4*)&comb[wq * 3072 + (8 + q) * 256 + lane * 4] = v4;
        }
    }
    __syncthreads();
    if (sh == 0) {
        #pragma unroll
        for (int dblk = 0; dblk < 2; ++dblk)
            #pragma unroll
            for (int q = 0; q < 4; ++q) {
                float4 v4 = *(const float4*)&comb[
                    wq * 3072 + (dblk * 4 + q) * 256 + lane * 4];
                oacc[dblk][q * 4 + 0] += v4.x; oacc[dblk][q * 4 + 1] += v4.y;
                oacc[dblk][q * 4 + 2] += v4.z; oacc[dblk][q * 4 + 3] += v4.w;
            }
        #pragma unroll
        for (int q = 0; q < 4; ++q) {
            float4 v4 = *(const float4*)&comb[
                wq * 3072 + (8 + q) * 256 + lane * 4];
            ol[q * 4 + 0] += v4.x; ol[q * 4 + 1] += v4.y;
            ol[q * 4 + 2] += v4.z; ol[q * 4 + 3] += v4.w;
        }
        // ---- epilogue: O / l (all-masked row: l=0 -> 0), store bf16 ----
        #pragma unroll
        for (int g = 0; g < 4; ++g)
            #pragma unroll
            for (int m = 0; m < 4; ++m) {
                const int reg = g * 4 + m;
                const int tr = m + 8 * g + 4 * hi;      // row within 32-block
                float l = ol[reg];
                float inv = (l > 0.f) ? 1.f / l : 0.f;
                int row = b * Tt + tw + tr;
                #pragma unroll
                for (int dblk = 0; dblk < 2; ++dblk)
                    out[(size_t)row * Dm + h * DHd + dblk * 32 + l31] =
                        f2bf(oacc[dblk][reg] * inv);
            }
    }
}

// ---------------------------------------------------------------------------
// out = LayerNorm(base + alpha*(d0[+d1]))*scale + bias.
// BASEBF: base is bf16. OUTF32 -> out fp32; OUTBF -> out_bf bf16.
// ---------------------------------------------------------------------------
template<int NPARTS, int BASEBF, int OUTF32, int OUTBF>
__global__ __launch_bounds__(256) void residual_ln_kernel(
    const void* __restrict__ base, const float* __restrict__ d0,
    const float* __restrict__ d1,
    const float* __restrict__ alpha_p, const float* __restrict__ scale,
    const float* __restrict__ bias, float* __restrict__ out,
    unsigned short* __restrict__ out_bf)
{
    const int row = blockIdx.x;
    const int tid = threadIdx.x;
    const float alpha = alpha_p[0];
    float4 xb;
    if (BASEBF) {
        bf16x4 bb = ((const bf16x4*)((const unsigned short*)base + (size_t)row * Dm))[tid];
        xb.x = (float)bb[0]; xb.y = (float)bb[1]; xb.z = (float)bb[2]; xb.w = (float)bb[3];
    } else {
        xb = ((const float4*)((const float*)base + (size_t)row * Dm))[tid];
    }
    float4 xd = ((const float4*)(d0 + (size_t)row * Dm))[tid];
    if (NPARTS == 2) {
        float4 x2 = ((const float4*)(d1 + (size_t)row * Dm))[tid];
        xd.x += x2.x; xd.y += x2.y; xd.z += x2.z; xd.w += x2.w;
    }
    float4 x;
    x.x = xb.x + alpha * xd.x;
    x.y = xb.y + alpha * xd.y;
    x.z = xb.z + alpha * xd.z;
    x.w = xb.w + alpha * xd.w;
    float s  = x.x + x.y + x.z + x.w;
    float sq = x.x*x.x + x.y*x.y + x.z*x.z + x.w*x.w;
    #pragma unroll
    for (int off = 32; off > 0; off >>= 1) {
        s  += __shfl_down(s, off, 64);
        sq += __shfl_down(sq, off, 64);
    }
    __shared__ float red[8];
    const int w = tid >> 6;
    if ((tid & 63) == 0) { red[w] = s; red[4 + w] = sq; }
    __syncthreads();
    s  = red[0] + red[1] + red[2] + red[3];
    sq = red[4] + red[5] + red[6] + red[7];
    const float mu  = s * (1.f / Dm);
    const float var = sq * (1.f / Dm) - mu * mu;
    const float r   = rsqrtf(var + 1e-5f);
    float4 sc = ((const float4*)scale)[tid];
    float4 bi = ((const float4*)bias)[tid];
    float4 o;
    o.x = (x.x - mu) * r * sc.x + bi.x;
    o.y = (x.y - mu) * r * sc.y + bi.y;
    o.z = (x.z - mu) * r * sc.z + bi.z;
    o.w = (x.w - mu) * r * sc.w + bi.w;
    if (OUTF32)
        ((float4*)(out + (size_t)row * Dm))[tid] = o;
    if (OUTBF)
        ((bf16x4*)(out_bf + (size_t)row * Dm))[tid] = pkbf4(o.x, o.y, o.z, o.w);
}

// ---------------------------------------------------------------------------
extern "C" void kernel_launch(void* const* d_in, const int* in_sizes, int n_in,
                              void* d_out, int out_size, void* d_ws, size_t ws_size,
                              hipStream_t stream)
{
    (void)in_sizes; (void)n_in; (void)out_size; (void)ws_size;
    const float* src  = (const float*)d_in[0];
    const int*   mask = (const int*)  d_in[1];
    const float* q_w  = (const float*)d_in[2];
    const float* q_b  = (const float*)d_in[3];
    const float* k_w  = (const float*)d_in[4];
    const float* k_b  = (const float*)d_in[5];
    const float* v_w  = (const float*)d_in[6];
    const float* v_b  = (const float*)d_in[7];
    const float* o_w  = (const float*)d_in[8];
    const float* o_b  = (const float*)d_in[9];
    const float* l1_w = (const float*)d_in[10];
    const float* l1_b = (const float*)d_in[11];
    const float* l2_w = (const float*)d_in[12];
    const float* l2_b = (const float*)d_in[13];
    const float* n1_s = (const float*)d_in[14];
    const float* n1_b = (const float*)d_in[15];
    const float* n2_s = (const float*)d_in[16];
    const float* n2_b = (const float*)d_in[17];
    const float* a_attn = (const float*)d_in[18];
    const float* a_ff   = (const float*)d_in[19];

    // ---- workspace layout (96 MB), lifetimes annotated ----
    const size_t MB = 1024 * 1024;
    char* w = (char*)d_ws;
    unsigned short* qkw  = (unsigned short*)(w + 0);        // [ 0, 4)   -> qkvt
    unsigned short* vw16 = (unsigned short*)(w + 4  * MB);  // [ 4, 6)   -> qkvt
    unsigned short* ow   = (unsigned short*)(w + 6  * MB);  // [ 6, 8)   -> O gemm
    unsigned short* l1w  = (unsigned short*)(w + 8  * MB);  // [ 8,16)   -> FFN1
    unsigned short* l2w  = (unsigned short*)(w + 16 * MB);  // [16,24)   -> FFN2
    unsigned short* srcb = (unsigned short*)(w + 24 * MB);  // [24,32)   -> qkvt
    unsigned short* qk16 = (unsigned short*)(w + 32 * MB);  // [32,48)   -> attn
    unsigned short* vtf  = (unsigned short*)(w + 48 * MB);  // [48,56)   -> attn
    unsigned*       mbT  = (unsigned*)      (w + 56 * MB);            // 512 KB
    float*          qkb  = (float*)         (w + 56 * MB + 524288);   // 8 KB
    // post-attention reuse:
    unsigned short* atb  = (unsigned short*)(w + 24 * MB);  // [24,32)   -> O gemm (srcb dead)
    float*          o0   = (float*)         (w + 58 * MB);  // [58,74)   -> LN1
    float*          o1   = (float*)         (w + 74 * MB);  // [74,90)   -> LN1
    unsigned short* x1b  = (unsigned short*)(w + 48 * MB);  // [48,56)   -> FFN1+LN2 (vtf dead)
    unsigned short* hb   = (unsigned short*)(w + 58 * MB);  // [58,90)   -> FFN2 (o0/o1 dead)
    float*          fp0  = (float*)         (w + 0);        // [ 0,16)   -> LN2 (qkw/vw16/ow dead)
    float*          fp1  = (float*)         (w + 32 * MB);  // [32,48)   -> LN2 (qk16 dead)

    const int MR = Bb * Tt;   // 4096
    dim3 blk(256);

    // 1) conversions + mask pack + bias concat
    preprocess_kernel<<<dim3(16904), blk, 0, stream>>>(
        q_w, k_w, v_w, o_w, l1_w, l2_w, src, mask, q_b, k_b,
        qkw, vw16, ow, l1w, l2w, srcb, mbT, qkb);
    // 2) merged QK + Vt GEMMs: 8-wave in-block split-K, identity mapping
    gemm_qkvt8_kernel<<<dim3(768), dim3(512), 0, stream>>>(
        srcb, qkw, vw16, qkb, v_b, qk16, vtf);
    // 3) MFMA flash attention -> atb bf16 (v5b, proven)
    attn_mfma_kernel<<<dim3(16, 32), dim3(512), 0, stream>>>(qk16, vtf, mbT, atb);
    // 4) O projection: splitk8 + XCD remap, z=2 -> fp32 partials
    gemm_splitk8_kernel<<<dim3(8, 32, 2), dim3(512), 0, stream>>>(
        atb, ow, o_b, o0, o1, Dm, Dm, 512);
    // 5) LN1 (sums O partials) -> x1b bf16 only
    residual_ln_kernel<2, 0, 0, 1><<<dim3(MR), blk, 0, stream>>>(
        src, o0, o1, a_attn, n1_s, n1_b, nullptr, x1b);
    // 6) FFN1 + ReLU -> bf16 hidden, 256x128 tile + XCD remap
    gemm_ffn1_kernel<<<dim3(32, 16), blk, 0, stream>>>(x1b, l1w, l1_b, hb);
    // 7) FFN2: splitk8 + XCD remap, z=2 -> fp32 partials
    gemm_splitk8_kernel<<<dim3(8, 32, 2), dim3(512), 0, stream>>>(
        hb, l2w, l2_b, fp0, fp1, Ff, Dm, 2048);
    // 8) LN2 (bf16 base x1b; sums FFN2 partials) -> final fp32 output
    residual_ln_kernel<2, 1, 1, 0><<<dim3(MR), blk, 0, stream>>>(
        x1b, fp0, fp1, a_ff, n2_s, n2_b, (float*)d_out, nullptr);
}

// Round 11
// 346.764 us; speedup vs baseline: 1.0900x; 1.0900x over previous
//
#include <hip/hip_runtime.h>
#include <math.h>

#define Dm 1024
#define Hh 16
#define DHd 64
#define Ff 4096
#define Tt 2048
#define Bb 2

#define ATT_C2 0.18033688011112042f   // 0.125 * log2(e), folded into Q at QK GEMM

typedef __bf16 bf16_8 __attribute__((ext_vector_type(8)));
typedef __bf16 bf16x2 __attribute__((ext_vector_type(2)));
typedef __bf16 bf16x4 __attribute__((ext_vector_type(4)));
typedef float  f32x4  __attribute__((ext_vector_type(4)));
typedef float  f32x16 __attribute__((ext_vector_type(16)));
typedef unsigned int u32x4 __attribute__((ext_vector_type(4)));
typedef unsigned int u32x8s __attribute__((ext_vector_type(8)));

__device__ __forceinline__ unsigned short f2bf(float f) {
    unsigned int u = __float_as_uint(f);
    unsigned int r = (u + 0x7fffu + ((u >> 16) & 1u)) >> 16;   // RNE
    return (unsigned short)r;
}

// native packed f32->bf16 (gfx950 v_cvt_pk_bf16_f32), RNE — fallback to cast
__device__ __forceinline__ bf16x2 pkbf(float a, float b) {
#if __has_builtin(__builtin_amdgcn_cvt_pk_bf16_f32)
    return __builtin_amdgcn_cvt_pk_bf16_f32(a, b);
#else
    bf16x2 r; r[0] = (__bf16)a; r[1] = (__bf16)b; return r;
#endif
}
__device__ __forceinline__ bf16x4 pkbf4(float a, float b, float c, float d) {
    bf16x2 lo = pkbf(a, b), hi = pkbf(c, d);
    return __builtin_shufflevector(lo, hi, 0, 1, 2, 3);
}

// v_permlane32_swap_b32: for lane l<32: a'=a[l], b'=a[l+32]; l>=32: a'=b[l-32], b'=b[l].
__device__ __forceinline__ void plswap32(unsigned &a, unsigned &b) {
#if __has_builtin(__builtin_amdgcn_permlane32_swap)
    auto r = __builtin_amdgcn_permlane32_swap((int)a, (int)b, false, false);
    a = (unsigned)r[0]; b = (unsigned)r[1];
#else
    asm volatile("v_permlane32_swap_b32 %0, %1" : "+v"(a), "+v"(b));
#endif
}

__device__ __forceinline__ void gld_lds16(const void* g, void* l) {
    __builtin_amdgcn_global_load_lds(
        (const __attribute__((address_space(1))) void*)g,
        (__attribute__((address_space(3))) void*)l,
        16, 0, 0);
}

// 32 consecutive u32 via scalar loads (off the VALU pipe). p must be
// wave-uniform. Outputs EARLY-CLOBBER ("=&s") so the allocator cannot
// overlap the input address pair with an output tuple (round-4 lesson).
__device__ __forceinline__ void sload32(const unsigned* p,
        u32x8s &a, u32x8s &b, u32x8s &c, u32x8s &d) {
    asm volatile(
        "s_load_dwordx8 %0, %4, 0x0\n\t"
        "s_load_dwordx8 %1, %4, 0x20\n\t"
        "s_load_dwordx8 %2, %4, 0x40\n\t"
        "s_load_dwordx8 %3, %4, 0x60\n\t"
        "s_waitcnt lgkmcnt(0)"
        : "=&s"(a), "=&s"(b), "=&s"(c), "=&s"(d)
        : "s"(p));
}

// select e where keep-bit set, else 0: one VALU op, mask from SGPR pair
__device__ __forceinline__ float selkeep(float e, unsigned long long keep) {
    float r;
    asm("v_cndmask_b32 %0, 0, %1, %2" : "=v"(r) : "v"(e), "s"(keep));
    return r;
}

// ---------------------------------------------------------------------------
// One-shot preprocess: all fp32->bf16 weight/src conversions + mask bit-pack
// (t-transposed, keep-inverted) + QK bias concat, in a single dispatch.
// ---------------------------------------------------------------------------
__global__ __launch_bounds__(256) void preprocess_kernel(
    const float* __restrict__ q_w, const float* __restrict__ k_w,
    const float* __restrict__ v_w, const float* __restrict__ o_w,
    const float* __restrict__ l1_w, const float* __restrict__ l2_w,
    const float* __restrict__ src, const int* __restrict__ mask,
    const float* __restrict__ q_b, const float* __restrict__ k_b,
    unsigned short* __restrict__ qkw, unsigned short* __restrict__ vw16,
    unsigned short* __restrict__ ow,  unsigned short* __restrict__ l1w,
    unsigned short* __restrict__ l2w, unsigned short* __restrict__ srcb,
    unsigned* __restrict__ mbT, float* __restrict__ qkb)
{
    const int bid = blockIdx.x;
    const int tid = threadIdx.x;
    if (bid < 16384) {                      // fp32 -> bf16, float4 granules
        int i = bid * 256 + tid;
        const float* sp; unsigned short* dp; int off;
        if (i < 1048576) {
            if (i < 262144)      { sp = q_w; dp = qkw;           off = i; }
            else if (i < 524288) { sp = k_w; dp = qkw + 1048576; off = i - 262144; }
            else if (i < 786432) { sp = v_w; dp = vw16;          off = i - 524288; }
            else                 { sp = o_w; dp = ow;            off = i - 786432; }
        } else if (i < 2097152)  { sp = l1_w; dp = l1w;          off = i - 1048576; }
        else if (i < 3145728)    { sp = l2_w; dp = l2w;          off = i - 2097152; }
        else                     { sp = src;  dp = srcb;         off = i - 3145728; }
        float4 v = ((const float4*)sp)[off];
        ((bf16x4*)dp)[off] = pkbf4(v.x, v.y, v.z, v.w);
    } else if (bid < 16896) {
        // mask [2048 t][2048 s] -> mbT[64][2048]: bit j of [tw32][s] =
        // KEEP (mask==0) for t = tw32*32+j. 131072 words, 1/thread.
        int w = (bid - 16384) * 256 + tid;
        int tw32 = w >> 11, s = w & 2047;
        const int* p = mask + (size_t)(tw32 * 32) * 2048 + s;
        unsigned bits = 0;
        #pragma unroll
        for (int j = 0; j < 32; ++j)
            bits |= (p[(size_t)j * 2048] == 0 ? 1u : 0u) << j;
        mbT[w] = bits;
    } else {                                // QK bias concat (2048)
        int i = (bid - 16896) * 256 + tid;
        qkb[i] = (i < 1024) ? q_b[i] : k_b[i - 1024];
    }
}

// ---------------------------------------------------------------------------
// Split-K GEMM with IN-BLOCK split-K over 8 waves. 128x128 tile, BK=128
// staged (64 KB LDS); waves 0-3 consume K-cols [0,64), waves 4-7 [64,128)
// -> 16 waves/CU (4/SIMD). kh=1 partials combined into kh=0 through the
// dead staging LDS. fp32 out; z=0 -> C (+bias), z=1 -> C2.
// XCD remap (kept — round-9 net win on these BW-pressured instances).
// Round-7 lesson: never raise min-waves past 4 (VGPR<=64 spills accs).
// Round-10 lesson: the qkvt variant of this structure triggered a 64-VGPR
// compiler bucket + scratch spill — keep THIS kernel's simple prologue.
// ---------------------------------------------------------------------------
__global__ __launch_bounds__(512, 4) void gemm_splitk8_kernel(
    const unsigned short* __restrict__ A, const unsigned short* __restrict__ W,
    const float* __restrict__ bias, float* __restrict__ C, float* __restrict__ C2,
    int K, int ldc, int ksub)
{
    __shared__ __align__(16) char smem[65536];
    __bf16* As = (__bf16*)smem;              // [128][128] 32 KB
    __bf16* Bs = (__bf16*)(smem + 32768);    // [128][128] 32 KB

    const int tid  = threadIdx.x;
    const int lane = tid & 63;
    const int wave = tid >> 6;               // 0..7
    const int wvu  = __builtin_amdgcn_readfirstlane(wave);
    const int wq   = wvu & 3;                // output sub-tile
    const int kh   = wvu >> 2;               // K-half of the staged 128 cols
    // ---- XCD remap: xcd = blockIdx.x (flat%8 on 8-wide grid) ----
    const int xcd = blockIdx.x;              // 0..7
    const int ib  = blockIdx.y;              // 0..31
    const int mq  = (xcd >> 1) * 8 + (ib & 7);    // 0..31
    const int nq  = (xcd & 1) * 4 + (ib >> 3);    // 0..7
    const int m0 = mq * 128;
    const int n0 = nq * 128;
    const int wm = (wq & 1) * 64;
    const int wn = (wq >> 1) * 64;
    const int quad = lane >> 4;
    const int lm = lane & 15;
    const int z  = blockIdx.z;
    const int kstart = z * ksub;
    float* Cz = (z == 0) ? C : C2;

    const int lr4 = lane >> 4;
    const int lc  = lane & 15;

    f32x4 acc[4][4];
    #pragma unroll
    for (int i = 0; i < 4; i++)
        #pragma unroll
        for (int j = 0; j < 4; j++) {
            acc[i][j][0] = 0.f; acc[i][j][1] = 0.f;
            acc[i][j][2] = 0.f; acc[i][j][3] = 0.f;
        }

    for (int k0 = kstart; k0 < kstart + ksub; k0 += 128) {
        __syncthreads();
        #pragma unroll
        for (int i = 0; i < 4; ++i) {
            int seg = wave * 4 + i;          // 0..31, 4 rows each
            int r = seg * 4 + lr4;           // 0..127
            int ch = lc ^ (r & 7);           // global chunk for swizzled LDS
            gld_lds16(A + (size_t)(m0 + r) * K + k0 + ch * 8, &As[seg * 512]);
            gld_lds16(W + (size_t)(n0 + r) * K + k0 + ch * 8, &Bs[seg * 512]);
        }
        __syncthreads();
        #pragma unroll
        for (int kk = 0; kk < 2; ++kk) {
            bf16_8 af[4], bfr[4];
            #pragma unroll
            for (int t = 0; t < 4; ++t) {
                int ra = wm + t * 16 + lm;
                int ca = (kh * 8 + kk * 4 + quad) ^ (ra & 7);
                af[t]  = *(const bf16_8*)&As[ra * 128 + ca * 8];
                int rb = wn + t * 16 + lm;
                int cb = (kh * 8 + kk * 4 + quad) ^ (rb & 7);
                bfr[t] = *(const bf16_8*)&Bs[rb * 128 + cb * 8];
            }
            #pragma unroll
            for (int i = 0; i < 4; i++)
                #pragma unroll
                for (int j = 0; j < 4; j++)
                    acc[i][j] = __builtin_amdgcn_mfma_f32_16x16x32_bf16(
                        af[i], bfr[j], acc[i][j], 0, 0, 0);
        }
    }

    // ---- combine kh=1 -> kh=0 through the (dead) staging LDS ----
    __syncthreads();
    float* comb = (float*)smem;
    if (kh == 1) {
        #pragma unroll
        for (int i = 0; i < 4; i++)
            #pragma unroll
            for (int j = 0; j < 4; j++)
                *(f32x4*)&comb[wq * 4096 + (i * 4 + j) * 256 + lane * 4] =
                    acc[i][j];
    }
    __syncthreads();
    if (kh == 0) {
        float bvc[4];
        #pragma unroll
        for (int j = 0; j < 4; j++)
            bvc[j] = (z == 0) ? bias[n0 + wn + j * 16 + lm] : 0.f;
        #pragma unroll
        for (int i = 0; i < 4; i++)
            #pragma unroll
            for (int j = 0; j < 4; j++) {
                f32x4 v4 = *(const f32x4*)&comb[
                    wq * 4096 + (i * 4 + j) * 256 + lane * 4];
                int col = n0 + wn + j * 16 + lm;
                #pragma unroll
                for (int r = 0; r < 4; r++) {
                    int row = m0 + wm + i * 16 + quad * 4 + r;
                    Cz[(size_t)row * ldc + col] = acc[i][j][r] + v4[r] + bvc[j];
                }
            }
    }
}

// ---------------------------------------------------------------------------
// Merged QK + Vt GEMM (768 blocks), BK=64 — round-8 4-wave version, verbatim.
// Round-10 post-mortem: the 8-wave conversion hit a 64-VGPR compiler bucket
// and spilled (WRITE 43MB vs 24.6MB outputs, VALUBusy 10%) -> 63.8us. The
// 4-wave identity-mapped version measured <=50us (round 8). Identity
// mapping kept: round-9 showed the XCD remap costs +10us here (latency-
// bound; concurrent blocks stop sharing A-panels in time).
// blocks [0,512):   qk16[4096,2048] = srcb @ [q_w;k_w]^T + qkb, Q cols xC2
// blocks [512,768): vtf [1024,4096] = vw16 @ srcb^T + v_b (row bias)
// ---------------------------------------------------------------------------
__global__ __launch_bounds__(256) void gemm_qkvt_kernel(
    const unsigned short* __restrict__ srcb, const unsigned short* __restrict__ qkw,
    const unsigned short* __restrict__ vw16, const float* __restrict__ qkb,
    const float* __restrict__ v_b,
    unsigned short* __restrict__ qk16, unsigned short* __restrict__ vtf)
{
    const int bid = blockIdx.x;
    const unsigned short *A, *W;
    const float* bias;
    unsigned short* C;
    int m0, n0, ldc;
    bool qscale, rowbias;
    if (bid < 512) {
        A = srcb; W = qkw; bias = qkb; C = qk16;
        n0 = (bid & 15) * 128; m0 = (bid >> 4) * 128;
        ldc = 2048; qscale = true; rowbias = false;
    } else {
        int b2 = bid - 512;
        A = vw16; W = srcb; bias = v_b; C = vtf;
        n0 = (b2 & 31) * 128; m0 = (b2 >> 5) * 128;
        ldc = 4096; qscale = false; rowbias = true;
    }
    const int K = 1024;

    __shared__ __bf16 As[128][64];
    __shared__ __bf16 Bs[128][64];
    const int tid  = threadIdx.x;
    const int lane = tid & 63;
    const int wave = tid >> 6;
    const int lr8 = lane >> 3;
    const int gch = (lane & 7) ^ lr8;
    const int wm = (wave & 1) * 64;
    const int wn = (wave >> 1) * 64;
    const int quad = lane >> 4;
    const int lm = lane & 15;

    f32x4 acc[4][4];
    #pragma unroll
    for (int i = 0; i < 4; i++)
        #pragma unroll
        for (int j = 0; j < 4; j++) {
            acc[i][j][0] = 0.f; acc[i][j][1] = 0.f;
            acc[i][j][2] = 0.f; acc[i][j][3] = 0.f;
        }

    for (int k0 = 0; k0 < K; k0 += 64) {
        __syncthreads();
        #pragma unroll
        for (int i = 0; i < 4; i++) {
            int seg = wave * 4 + i;
            int r = seg * 8 + lr8;
            gld_lds16(A + (size_t)(m0 + r) * K + k0 + gch * 8, &As[seg * 8][0]);
            gld_lds16(W + (size_t)(n0 + r) * K + k0 + gch * 8, &Bs[seg * 8][0]);
        }
        __syncthreads();
        #pragma unroll
        for (int kh = 0; kh < 2; kh++) {
            bf16_8 af[4], bfr[4];
            #pragma unroll
            for (int t = 0; t < 4; t++) {
                int ch = (kh * 4 + quad) ^ (lm & 7);
                af[t]  = *(const bf16_8*)&As[wm + t * 16 + lm][ch * 8];
                bfr[t] = *(const bf16_8*)&Bs[wn + t * 16 + lm][ch * 8];
            }
            #pragma unroll
            for (int i = 0; i < 4; i++)
                #pragma unroll
                for (int j = 0; j < 4; j++)
                    acc[i][j] = __builtin_amdgcn_mfma_f32_16x16x32_bf16(
                        af[i], bfr[j], acc[i][j], 0, 0, 0);
        }
    }

    float bvc[4];
    float brr[4][4];
    if (!rowbias) {
        #pragma unroll
        for (int j = 0; j < 4; j++) bvc[j] = bias[n0 + wn + j * 16 + lm];
    } else {
        #pragma unroll
        for (int i = 0; i < 4; i++) {
            float4 t4 = *(const float4*)&bias[m0 + wm + i * 16 + quad * 4];
            brr[i][0] = t4.x; brr[i][1] = t4.y; brr[i][2] = t4.z; brr[i][3] = t4.w;
        }
    }

    #pragma unroll
    for (int i = 0; i < 4; i++)
        #pragma unroll
        for (int j = 0; j < 4; j++) {
            int col = n0 + wn + j * 16 + lm;
            #pragma unroll
            for (int r = 0; r < 4; r++) {
                int row = m0 + wm + i * 16 + quad * 4 + r;
                float v = acc[i][j][r] + (rowbias ? brr[i][r] : bvc[j]);
                if (qscale && col < 1024) v *= ATT_C2;
                C[(size_t)row * ldc + col] = f2bf(v);
            }
        }
}

// ---------------------------------------------------------------------------
// FFN1 GEMM: hb[4096,4096] = relu(x1b[4096,1024] @ l1w[4096,1024]^T + l1_b).
// 256x128 tile, BK=64, LDS 48 KB, acc 4x8 per wave. 512 blocks = 2/CU exact.
// XCD remap kept (round-9 net win).
// ---------------------------------------------------------------------------
__global__ __launch_bounds__(256, 2) void gemm_ffn1_kernel(
    const unsigned short* __restrict__ A, const unsigned short* __restrict__ W,
    const float* __restrict__ bias, unsigned short* __restrict__ C)
{
    __shared__ __bf16 As[256][64];   // 32 KB
    __shared__ __bf16 Bs[128][64];   // 16 KB
    const int tid  = threadIdx.x;
    const int lane = tid & 63;
    const int wave = tid >> 6;
    // ---- XCD remap ----
    const int f   = blockIdx.x + (blockIdx.y << 5);  // 0..511
    const int xcd = f & 7;
    const int ib  = f >> 3;                          // 0..63
    const int mq  = (xcd >> 1) * 4 + (ib & 3);       // 0..15
    const int nq  = (xcd & 1) * 16 + (ib >> 2);      // 0..31
    const int m0 = mq * 256;
    const int n0 = nq * 128;
    const int lr8 = lane >> 3;
    const int gch = (lane & 7) ^ lr8;
    const int quad = lane >> 4;
    const int lm = lane & 15;

    f32x4 acc[4][8];
    #pragma unroll
    for (int i = 0; i < 4; i++)
        #pragma unroll
        for (int j = 0; j < 8; j++) {
            acc[i][j][0] = 0.f; acc[i][j][1] = 0.f;
            acc[i][j][2] = 0.f; acc[i][j][3] = 0.f;
        }

    for (int k0 = 0; k0 < 1024; k0 += 64) {
        __syncthreads();
        #pragma unroll
        for (int i = 0; i < 8; i++) {          // A: 8 segments/wave
            int seg = wave * 8 + i;
            int r = seg * 8 + lr8;
            gld_lds16(A + (size_t)(m0 + r) * 1024 + k0 + gch * 8, &As[seg * 8][0]);
        }
        #pragma unroll
        for (int i = 0; i < 4; i++) {          // B: 4 segments/wave
            int seg = wave * 4 + i;
            int r = seg * 8 + lr8;
            gld_lds16(W + (size_t)(n0 + r) * 1024 + k0 + gch * 8, &Bs[seg * 8][0]);
        }
        __syncthreads();
        #pragma unroll
        for (int kh = 0; kh < 2; kh++) {
            const int ch = (kh * 4 + quad) ^ (lm & 7);
            bf16_8 af[4], bfr[8];
            #pragma unroll
            for (int t = 0; t < 4; t++)
                af[t] = *(const bf16_8*)&As[wave * 64 + t * 16 + lm][ch * 8];
            #pragma unroll
            for (int j = 0; j < 8; j++)
                bfr[j] = *(const bf16_8*)&Bs[j * 16 + lm][ch * 8];
            #pragma unroll
            for (int i = 0; i < 4; i++)
                #pragma unroll
                for (int j = 0; j < 8; j++)
                    acc[i][j] = __builtin_amdgcn_mfma_f32_16x16x32_bf16(
                        af[i], bfr[j], acc[i][j], 0, 0, 0);
        }
    }

    float bv[8];
    #pragma unroll
    for (int j = 0; j < 8; j++) bv[j] = bias[n0 + j * 16 + lm];

    #pragma unroll
    for (int i = 0; i < 4; i++)
        #pragma unroll
        for (int j = 0; j < 8; j++) {
            int col = n0 + j * 16 + lm;
            #pragma unroll
            for (int r = 0; r < 4; r++) {
                int row = m0 + wave * 64 + i * 16 + quad * 4 + r;
                float v = fmaxf(acc[i][j][r] + bv[j], 0.f);
                C[(size_t)row * Ff + col] = f2bf(v);
            }
        }
}

// ---------------------------------------------------------------------------
// MFMA flash attention v5b (proven 50.1us, 56 VGPR, 16 waves/CU).
// Round-8 A/B: s_setprio null -> removed. Round-7: never 8 waves/SIMD here.
// Wave pairs (wq, wq+4) share one 32-t range; sh=wave>>2 picks s-blocks
// {0,1} or {2,3} of each 128-s tile. O/l partial combine through LDS.
// 512 thr, K/V double-buffered 64 KB, grid (16,32) = 2 blk/CU.
// ---------------------------------------------------------------------------
__global__ __launch_bounds__(512, 4) void attn_mfma_kernel(
    const unsigned short* __restrict__ qk,
    const unsigned short* __restrict__ vt,
    const unsigned* __restrict__ mbT,
    unsigned short* __restrict__ out)
{
    __shared__ __align__(16) char smem[65536];
    __bf16* KsP = (__bf16*)smem;             // [2][8192] = 2 x 16 KB
    __bf16* VtP = (__bf16*)(smem + 32768);   // [2][8192] = 2 x 16 KB

    const int tid  = threadIdx.x;
    const int lane = tid & 63;
    const int wave = tid >> 6;           // 0..7
    const int l31  = lane & 31;
    const int hi   = lane >> 5;
    const int x7   = l31 & 7;
    const int bh = blockIdx.y;
    const int b = bh >> 4, h = bh & 15;
    // wave-uniform (SGPR) wave decomposition: wq = t-range, sh = s-half
    const int wvu = __builtin_amdgcn_readfirstlane(wave);
    const int wq  = wvu & 3;
    const int sh  = wvu >> 2;
    const int tw = blockIdx.x * 128 + wq * 32;
    const unsigned* mrow = mbT + (size_t)(blockIdx.x * 4 + wq) * 2048;

    // Q B-frags: B[k=hi*8+j][col=t=l31], 4 dsteps of 16 covering d=0..63
    bf16_8 qf[4];
    #pragma unroll
    for (int ds4 = 0; ds4 < 4; ++ds4)
        qf[ds4] = *(const bf16_8*)(qk +
            (size_t)(b * Tt + tw + l31) * 2048 + h * DHd + ds4 * 16 + hi * 8);

    f32x16 oacc[2];
    f32x16 ol;
    f32x16 z16;
    #pragma unroll
    for (int r = 0; r < 16; ++r) {
        oacc[0][r] = 0.f; oacc[1][r] = 0.f; ol[r] = 0.f; z16[r] = 0.f;
    }
    bf16_8 vone;
    {
        __bf16 one = (__bf16)1.0f;
        #pragma unroll
        for (int j = 0; j < 8; ++j) vone[j] = one;
    }

    const int krow8 = lane >> 3;
    const int kj    = (lane & 7) ^ krow8;    // K staging swizzle
    const int vr4   = lane >> 4;

    auto STAGE = [&](int nb, int s0) {
        #pragma unroll
        for (int i = 0; i < 2; ++i) {
            int ci = wave * 2 + i;           // 0..15
            {
                int r = 8 * ci + krow8;
                const unsigned short* g = qk +
                    (size_t)(b * Tt + s0 + r) * 2048 + 1024 + h * DHd + kj * 8;
                gld_lds16(g, &KsP[nb * 8192 + ci * 512]);
            }
            {
                int d = 4 * ci + vr4;
                int jj = (lane & 15) ^ (d & 7);
                const unsigned short* g = vt +
                    (size_t)(h * DHd + d) * 4096 + b * Tt + s0 + jj * 8;
                gld_lds16(g, &VtP[nb * 8192 + ci * 512]);
            }
        }
    };

    STAGE(0, 0);

    for (int st = 0; st < 16; ++st) {
        const int cb = st & 1;
        const int s0 = st * 128;
        __syncthreads();                     // buf[cb] staged; buf[cb^1] free

        if (st < 15) STAGE(cb ^ 1, s0 + 128);

        #pragma unroll
        for (int sbl = 0; sbl < 2; ++sbl) {
            const int sb = sh * 2 + sbl;     // this wave's s-block (uniform)
            // keep-bit words for s = s0+sb*32 .. +31 (scalar pipe)
            u32x8s ma, mbw, mc, md;
            sload32(mrow + s0 + sb * 32, ma, mbw, mc, md);

            // ---- S^T: 32 s x 32 t, K streamed from LDS, Q in regs ----
            f32x16 sacc = z16;
            #pragma unroll
            for (int ds4 = 0; ds4 < 4; ++ds4) {
                bf16_8 kf = *(const bf16_8*)&KsP[cb * 8192 +
                    (sb * 32 + l31) * 64 + (((ds4 * 2 + hi) ^ x7) * 8)];
                sacc = __builtin_amdgcn_mfma_f32_32x32x16_bf16(
                    kf, qf[ds4], sacc, 0, 0, 0);
            }
            // ---- exp2 + SGPR-mask select (1 cndmask/elem) ----
            float p[16];
            #pragma unroll
            for (int g = 0; g < 4; ++g) {
                u32x8s vv = (g == 0) ? ma : (g == 1) ? mbw : (g == 2) ? mc : md;
                #pragma unroll
                for (int m = 0; m < 4; ++m) {
                    const int reg = g * 4 + m;
                    unsigned long long keep =
                        ((unsigned long long)vv[m + 4] << 32) |
                        (unsigned long long)vv[m];
                    float e = __builtin_amdgcn_exp2f(sacc[reg]);
                    p[reg] = selkeep(e, keep);
                }
            }
            // ---- in-register repack to PV A-frags (T12) ----
            unsigned u[4], v[4];
            #pragma unroll
            for (int g = 0; g < 4; ++g) {
                u[g] = __builtin_bit_cast(unsigned, pkbf(p[g * 4 + 0], p[g * 4 + 1]));
                v[g] = __builtin_bit_cast(unsigned, pkbf(p[g * 4 + 2], p[g * 4 + 3]));
            }
            plswap32(u[0], u[1]); plswap32(v[0], v[1]);   // kstep0: s 0..15
            plswap32(u[2], u[3]); plswap32(v[2], v[3]);   // kstep1: s 16..31
            u32x4 w0; w0[0] = u[0]; w0[1] = v[0]; w0[2] = u[1]; w0[3] = v[1];
            u32x4 w1; w1[0] = u[2]; w1[1] = v[2]; w1[2] = u[3]; w1[3] = v[3];
            bf16_8 pa0 = __builtin_bit_cast(bf16_8, w0);
            bf16_8 pa1 = __builtin_bit_cast(bf16_8, w1);
            // ---- PV + l: O[t][d] += P V, l[t] += P·1 ----
            #pragma unroll
            for (int kst = 0; kst < 2; ++kst) {
                bf16_8 pa = kst ? pa1 : pa0;
                #pragma unroll
                for (int dblk = 0; dblk < 2; ++dblk) {
                    int cpos = (sb * 4 + kst * 2 + hi) ^ x7;
                    bf16_8 vf = *(const bf16_8*)&VtP[cb * 8192 +
                        ((dblk * 32 + l31) * 16 + cpos) * 8];
                    oacc[dblk] = __builtin_amdgcn_mfma_f32_32x32x16_bf16(
                        pa, vf, oacc[dblk], 0, 0, 0);
                }
                ol = __builtin_amdgcn_mfma_f32_32x32x16_bf16(
                    pa, vone, ol, 0, 0, 0);
            }
        }
    }

    // ---- combine wave-pair partials (sh=1 -> sh=0) through LDS ----
    // layout: comb[wq*3072 + piece*256 + lane*4], piece 0..7 = oacc, 8..11 = ol
    __syncthreads();                         // all compute done; K/V dead
    float* comb = (float*)smem;              // 48 KB of the 64 KB
    if (sh == 1) {
        #pragma unroll
        for (int dblk = 0; dblk < 2; ++dblk)
            #pragma unroll
            for (int q = 0; q < 4; ++q) {
                float4 v4 = { oacc[dblk][q * 4 + 0], oacc[dblk][q * 4 + 1],
                              oacc[dblk][q * 4 + 2], oacc[dblk][q * 4 + 3] };
                *(float4*)&comb[wq * 3072 + (dblk * 4 + q) * 256 + lane * 4] = v4;
            }
        #pragma unroll
        for (int q = 0; q < 4; ++q) {
            float4 v4 = { ol[q * 4 + 0], ol[q * 4 + 1],
                          ol[q * 4 + 2], ol[q * 4 + 3] };
            *(float4*)&comb[wq * 3072 + (8 + q) * 256 + lane * 4] = v4;
        }
    }
    __syncthreads();
    if (sh == 0) {
        #pragma unroll
        for (int dblk = 0; dblk < 2; ++dblk)
            #pragma unroll
            for (int q = 0; q < 4; ++q) {
                float4 v4 = *(const float4*)&comb[
                    wq * 3072 + (dblk * 4 + q) * 256 + lane * 4];
                oacc[dblk][q * 4 + 0] += v4.x; oacc[dblk][q * 4 + 1] += v4.y;
                oacc[dblk][q * 4 + 2] += v4.z; oacc[dblk][q * 4 + 3] += v4.w;
            }
        #pragma unroll
        for (int q = 0; q < 4; ++q) {
            float4 v4 = *(const float4*)&comb[
                wq * 3072 + (8 + q) * 256 + lane * 4];
            ol[q * 4 + 0] += v4.x; ol[q * 4 + 1] += v4.y;
            ol[q * 4 + 2] += v4.z; ol[q * 4 + 3] += v4.w;
        }
        // ---- epilogue: O / l (all-masked row: l=0 -> 0), store bf16 ----
        #pragma unroll
        for (int g = 0; g < 4; ++g)
            #pragma unroll
            for (int m = 0; m < 4; ++m) {
                const int reg = g * 4 + m;
                const int tr = m + 8 * g + 4 * hi;      // row within 32-block
                float l = ol[reg];
                float inv = (l > 0.f) ? 1.f / l : 0.f;
                int row = b * Tt + tw + tr;
                #pragma unroll
                for (int dblk = 0; dblk < 2; ++dblk)
                    out[(size_t)row * Dm + h * DHd + dblk * 32 + l31] =
                        f2bf(oacc[dblk][reg] * inv);
            }
    }
}

// ---------------------------------------------------------------------------
// out = LayerNorm(base + alpha*(d0[+d1]))*scale + bias.
// BASEBF: base is bf16. OUTF32 -> out fp32; OUTBF -> out_bf bf16.
// ---------------------------------------------------------------------------
template<int NPARTS, int BASEBF, int OUTF32, int OUTBF>
__global__ __launch_bounds__(256) void residual_ln_kernel(
    const void* __restrict__ base, const float* __restrict__ d0,
    const float* __restrict__ d1,
    const float* __restrict__ alpha_p, const float* __restrict__ scale,
    const float* __restrict__ bias, float* __restrict__ out,
    unsigned short* __restrict__ out_bf)
{
    const int row = blockIdx.x;
    const int tid = threadIdx.x;
    const float alpha = alpha_p[0];
    float4 xb;
    if (BASEBF) {
        bf16x4 bb = ((const bf16x4*)((const unsigned short*)base + (size_t)row * Dm))[tid];
        xb.x = (float)bb[0]; xb.y = (float)bb[1]; xb.z = (float)bb[2]; xb.w = (float)bb[3];
    } else {
        xb = ((const float4*)((const float*)base + (size_t)row * Dm))[tid];
    }
    float4 xd = ((const float4*)(d0 + (size_t)row * Dm))[tid];
    if (NPARTS == 2) {
        float4 x2 = ((const float4*)(d1 + (size_t)row * Dm))[tid];
        xd.x += x2.x; xd.y += x2.y; xd.z += x2.z; xd.w += x2.w;
    }
    float4 x;
    x.x = xb.x + alpha * xd.x;
    x.y = xb.y + alpha * xd.y;
    x.z = xb.z + alpha * xd.z;
    x.w = xb.w + alpha * xd.w;
    float s  = x.x + x.y + x.z + x.w;
    float sq = x.x*x.x + x.y*x.y + x.z*x.z + x.w*x.w;
    #pragma unroll
    for (int off = 32; off > 0; off >>= 1) {
        s  += __shfl_down(s, off, 64);
        sq += __shfl_down(sq, off, 64);
    }
    __shared__ float red[8];
    const int w = tid >> 6;
    if ((tid & 63) == 0) { red[w] = s; red[4 + w] = sq; }
    __syncthreads();
    s  = red[0] + red[1] + red[2] + red[3];
    sq = red[4] + red[5] + red[6] + red[7];
    const float mu  = s * (1.f / Dm);
    const float var = sq * (1.f / Dm) - mu * mu;
    const float r   = rsqrtf(var + 1e-5f);
    float4 sc = ((const float4*)scale)[tid];
    float4 bi = ((const float4*)bias)[tid];
    float4 o;
    o.x = (x.x - mu) * r * sc.x + bi.x;
    o.y = (x.y - mu) * r * sc.y + bi.y;
    o.z = (x.z - mu) * r * sc.z + bi.z;
    o.w = (x.w - mu) * r * sc.w + bi.w;
    if (OUTF32)
        ((float4*)(out + (size_t)row * Dm))[tid] = o;
    if (OUTBF)
        ((bf16x4*)(out_bf + (size_t)row * Dm))[tid] = pkbf4(o.x, o.y, o.z, o.w);
}

// ---------------------------------------------------------------------------
extern "C" void kernel_launch(void* const* d_in, const int* in_sizes, int n_in,
                              void* d_out, int out_size, void* d_ws, size_t ws_size,
                              hipStream_t stream)
{
    (void)in_sizes; (void)n_in; (void)out_size; (void)ws_size;
    const float* src  = (const float*)d_in[0];
    const int*   mask = (const int*)  d_in[1];
    const float* q_w  = (const float*)d_in[2];
    const float* q_b  = (const float*)d_in[3];
    const float* k_w  = (const float*)d_in[4];
    const float* k_b  = (const float*)d_in[5];
    const float* v_w  = (const float*)d_in[6];
    const float* v_b  = (const float*)d_in[7];
    const float* o_w  = (const float*)d_in[8];
    const float* o_b  = (const float*)d_in[9];
    const float* l1_w = (const float*)d_in[10];
    const float* l1_b = (const float*)d_in[11];
    const float* l2_w = (const float*)d_in[12];
    const float* l2_b = (const float*)d_in[13];
    const float* n1_s = (const float*)d_in[14];
    const float* n1_b = (const float*)d_in[15];
    const float* n2_s = (const float*)d_in[16];
    const float* n2_b = (const float*)d_in[17];
    const float* a_attn = (const float*)d_in[18];
    const float* a_ff   = (const float*)d_in[19];

    // ---- workspace layout (96 MB), lifetimes annotated ----
    const size_t MB = 1024 * 1024;
    char* w = (char*)d_ws;
    unsigned short* qkw  = (unsigned short*)(w + 0);        // [ 0, 4)   -> qkvt
    unsigned short* vw16 = (unsigned short*)(w + 4  * MB);  // [ 4, 6)   -> qkvt
    unsigned short* ow   = (unsigned short*)(w + 6  * MB);  // [ 6, 8)   -> O gemm
    unsigned short* l1w  = (unsigned short*)(w + 8  * MB);  // [ 8,16)   -> FFN1
    unsigned short* l2w  = (unsigned short*)(w + 16 * MB);  // [16,24)   -> FFN2
    unsigned short* srcb = (unsigned short*)(w + 24 * MB);  // [24,32)   -> qkvt
    unsigned short* qk16 = (unsigned short*)(w + 32 * MB);  // [32,48)   -> attn
    unsigned short* vtf  = (unsigned short*)(w + 48 * MB);  // [48,56)   -> attn
    unsigned*       mbT  = (unsigned*)      (w + 56 * MB);            // 512 KB
    float*          qkb  = (float*)         (w + 56 * MB + 524288);   // 8 KB
    // post-attention reuse:
    unsigned short* atb  = (unsigned short*)(w + 24 * MB);  // [24,32)   -> O gemm (srcb dead)
    float*          o0   = (float*)         (w + 58 * MB);  // [58,74)   -> LN1
    float*          o1   = (float*)         (w + 74 * MB);  // [74,90)   -> LN1
    unsigned short* x1b  = (unsigned short*)(w + 48 * MB);  // [48,56)   -> FFN1+LN2 (vtf dead)
    unsigned short* hb   = (unsigned short*)(w + 58 * MB);  // [58,90)   -> FFN2 (o0/o1 dead)
    float*          fp0  = (float*)         (w + 0);        // [ 0,16)   -> LN2 (qkw/vw16/ow dead)
    float*          fp1  = (float*)         (w + 32 * MB);  // [32,48)   -> LN2 (qk16 dead)

    const int MR = Bb * Tt;   // 4096
    dim3 blk(256);

    // 1) conversions + mask pack + bias concat
    preprocess_kernel<<<dim3(16904), blk, 0, stream>>>(
        q_w, k_w, v_w, o_w, l1_w, l2_w, src, mask, q_b, k_b,
        qkw, vw16, ow, l1w, l2w, srcb, mbT, qkb);
    // 2) merged QK + Vt GEMMs: 4-wave, identity mapping (round-8 proven)
    gemm_qkvt_kernel<<<dim3(768), blk, 0, stream>>>(
        srcb, qkw, vw16, qkb, v_b, qk16, vtf);
    // 3) MFMA flash attention -> atb bf16 (v5b, proven)
    attn_mfma_kernel<<<dim3(16, 32), dim3(512), 0, stream>>>(qk16, vtf, mbT, atb);
    // 4) O projection: splitk8 + XCD remap, z=2 -> fp32 partials
    gemm_splitk8_kernel<<<dim3(8, 32, 2), dim3(512), 0, stream>>>(
        atb, ow, o_b, o0, o1, Dm, Dm, 512);
    // 5) LN1 (sums O partials) -> x1b bf16 only
    residual_ln_kernel<2, 0, 0, 1><<<dim3(MR), blk, 0, stream>>>(
        src, o0, o1, a_attn, n1_s, n1_b, nullptr, x1b);
    // 6) FFN1 + ReLU -> bf16 hidden, 256x128 tile + XCD remap
    gemm_ffn1_kernel<<<dim3(32, 16), blk, 0, stream>>>(x1b, l1w, l1_b, hb);
    // 7) FFN2: splitk8 + XCD remap, z=2 -> fp32 partials
    gemm_splitk8_kernel<<<dim3(8, 32, 2), dim3(512), 0, stream>>>(
        hb, l2w, l2_b, fp0, fp1, Ff, Dm, 2048);
    // 8) LN2 (bf16 base x1b; sums FFN2 partials) -> final fp32 output
    residual_ln_kernel<2, 1, 1, 0><<<dim3(MR), blk, 0, stream>>>(
        x1b, fp0, fp1, a_ff, n2_s, n2_b, (float*)d_out, nullptr);
}

// Round 12
// 334.477 us; speedup vs baseline: 1.1300x; 1.0367x over previous
//
#include <hip/hip_runtime.h>
#include <math.h>

#define Dm 1024
#define Hh 16
#define DHd 64
#define Ff 4096
#define Tt 2048
#define Bb 2

#define ATT_C2 0.18033688011112042f   // 0.125 * log2(e), folded into Q at QK GEMM

typedef __bf16 bf16_8 __attribute__((ext_vector_type(8)));
typedef __bf16 bf16x2 __attribute__((ext_vector_type(2)));
typedef __bf16 bf16x4 __attribute__((ext_vector_type(4)));
typedef float  f32x4  __attribute__((ext_vector_type(4)));
typedef float  f32x16 __attribute__((ext_vector_type(16)));
typedef unsigned int u32x4 __attribute__((ext_vector_type(4)));
typedef unsigned int u32x8s __attribute__((ext_vector_type(8)));

__device__ __forceinline__ unsigned short f2bf(float f) {
    unsigned int u = __float_as_uint(f);
    unsigned int r = (u + 0x7fffu + ((u >> 16) & 1u)) >> 16;   // RNE
    return (unsigned short)r;
}

// native packed f32->bf16 (gfx950 v_cvt_pk_bf16_f32), RNE — fallback to cast
__device__ __forceinline__ bf16x2 pkbf(float a, float b) {
#if __has_builtin(__builtin_amdgcn_cvt_pk_bf16_f32)
    return __builtin_amdgcn_cvt_pk_bf16_f32(a, b);
#else
    bf16x2 r; r[0] = (__bf16)a; r[1] = (__bf16)b; return r;
#endif
}
__device__ __forceinline__ bf16x4 pkbf4(float a, float b, float c, float d) {
    bf16x2 lo = pkbf(a, b), hi = pkbf(c, d);
    return __builtin_shufflevector(lo, hi, 0, 1, 2, 3);
}

// v_permlane32_swap_b32: for lane l<32: a'=a[l], b'=a[l+32]; l>=32: a'=b[l-32], b'=b[l].
__device__ __forceinline__ void plswap32(unsigned &a, unsigned &b) {
#if __has_builtin(__builtin_amdgcn_permlane32_swap)
    auto r = __builtin_amdgcn_permlane32_swap((int)a, (int)b, false, false);
    a = (unsigned)r[0]; b = (unsigned)r[1];
#else
    asm volatile("v_permlane32_swap_b32 %0, %1" : "+v"(a), "+v"(b));
#endif
}

__device__ __forceinline__ void gld_lds16(const void* g, void* l) {
    __builtin_amdgcn_global_load_lds(
        (const __attribute__((address_space(1))) void*)g,
        (__attribute__((address_space(3))) void*)l,
        16, 0, 0);
}

// 32 consecutive u32 via scalar loads (off the VALU pipe). p must be
// wave-uniform. Outputs EARLY-CLOBBER ("=&s") so the allocator cannot
// overlap the input address pair with an output tuple (round-4 lesson).
__device__ __forceinline__ void sload32(const unsigned* p,
        u32x8s &a, u32x8s &b, u32x8s &c, u32x8s &d) {
    asm volatile(
        "s_load_dwordx8 %0, %4, 0x0\n\t"
        "s_load_dwordx8 %1, %4, 0x20\n\t"
        "s_load_dwordx8 %2, %4, 0x40\n\t"
        "s_load_dwordx8 %3, %4, 0x60\n\t"
        "s_waitcnt lgkmcnt(0)"
        : "=&s"(a), "=&s"(b), "=&s"(c), "=&s"(d)
        : "s"(p));
}

// select e where keep-bit set, else 0: one VALU op, mask from SGPR pair
__device__ __forceinline__ float selkeep(float e, unsigned long long keep) {
    float r;
    asm("v_cndmask_b32 %0, 0, %1, %2" : "=v"(r) : "v"(e), "s"(keep));
    return r;
}

// ---------------------------------------------------------------------------
// One-shot preprocess: all fp32->bf16 weight/src conversions + mask bit-pack
// (t-transposed, keep-inverted) + QK bias concat, in a single dispatch.
// ---------------------------------------------------------------------------
__global__ __launch_bounds__(256) void preprocess_kernel(
    const float* __restrict__ q_w, const float* __restrict__ k_w,
    const float* __restrict__ v_w, const float* __restrict__ o_w,
    const float* __restrict__ l1_w, const float* __restrict__ l2_w,
    const float* __restrict__ src, const int* __restrict__ mask,
    const float* __restrict__ q_b, const float* __restrict__ k_b,
    unsigned short* __restrict__ qkw, unsigned short* __restrict__ vw16,
    unsigned short* __restrict__ ow,  unsigned short* __restrict__ l1w,
    unsigned short* __restrict__ l2w, unsigned short* __restrict__ srcb,
    unsigned* __restrict__ mbT, float* __restrict__ qkb)
{
    const int bid = blockIdx.x;
    const int tid = threadIdx.x;
    if (bid < 16384) {                      // fp32 -> bf16, float4 granules
        int i = bid * 256 + tid;
        const float* sp; unsigned short* dp; int off;
        if (i < 1048576) {
            if (i < 262144)      { sp = q_w; dp = qkw;           off = i; }
            else if (i < 524288) { sp = k_w; dp = qkw + 1048576; off = i - 262144; }
            else if (i < 786432) { sp = v_w; dp = vw16;          off = i - 524288; }
            else                 { sp = o_w; dp = ow;            off = i - 786432; }
        } else if (i < 2097152)  { sp = l1_w; dp = l1w;          off = i - 1048576; }
        else if (i < 3145728)    { sp = l2_w; dp = l2w;          off = i - 2097152; }
        else                     { sp = src;  dp = srcb;         off = i - 3145728; }
        float4 v = ((const float4*)sp)[off];
        ((bf16x4*)dp)[off] = pkbf4(v.x, v.y, v.z, v.w);
    } else if (bid < 16896) {
        // mask [2048 t][2048 s] -> mbT[64][2048]: bit j of [tw32][s] =
        // KEEP (mask==0) for t = tw32*32+j. 131072 words, 1/thread.
        int w = (bid - 16384) * 256 + tid;
        int tw32 = w >> 11, s = w & 2047;
        const int* p = mask + (size_t)(tw32 * 32) * 2048 + s;
        unsigned bits = 0;
        #pragma unroll
        for (int j = 0; j < 32; ++j)
            bits |= (p[(size_t)j * 2048] == 0 ? 1u : 0u) << j;
        mbT[w] = bits;
    } else {                                // QK bias concat (2048)
        int i = (bid - 16896) * 256 + tid;
        qkb[i] = (i < 1024) ? q_b[i] : k_b[i - 1024];
    }
}

// ---------------------------------------------------------------------------
// Split-K GEMM with IN-BLOCK split-K over 8 waves. 128x128 tile, BK=128
// staged (64 KB LDS); waves 0-3 consume K-cols [0,64), waves 4-7 [64,128)
// -> 16 waves/CU (4/SIMD). kh=1 partials combined into kh=0 through the
// dead staging LDS. fp32 out; z=0 -> C (+bias), z=1 -> C2.
// XCD remap (kept — round-9 net win on these BW-pressured instances).
// Round-7 lesson: never raise min-waves past 4 (VGPR<=64 spills accs).
// Round-10 lesson: the qkvt variant of this structure triggered a 64-VGPR
// compiler bucket + scratch spill — keep THIS kernel's simple prologue.
// ---------------------------------------------------------------------------
__global__ __launch_bounds__(512, 4) void gemm_splitk8_kernel(
    const unsigned short* __restrict__ A, const unsigned short* __restrict__ W,
    const float* __restrict__ bias, float* __restrict__ C, float* __restrict__ C2,
    int K, int ldc, int ksub)
{
    __shared__ __align__(16) char smem[65536];
    __bf16* As = (__bf16*)smem;              // [128][128] 32 KB
    __bf16* Bs = (__bf16*)(smem + 32768);    // [128][128] 32 KB

    const int tid  = threadIdx.x;
    const int lane = tid & 63;
    const int wave = tid >> 6;               // 0..7
    const int wvu  = __builtin_amdgcn_readfirstlane(wave);
    const int wq   = wvu & 3;                // output sub-tile
    const int kh   = wvu >> 2;               // K-half of the staged 128 cols
    // ---- XCD remap: xcd = blockIdx.x (flat%8 on 8-wide grid) ----
    const int xcd = blockIdx.x;              // 0..7
    const int ib  = blockIdx.y;              // 0..31
    const int mq  = (xcd >> 1) * 8 + (ib & 7);    // 0..31
    const int nq  = (xcd & 1) * 4 + (ib >> 3);    // 0..7
    const int m0 = mq * 128;
    const int n0 = nq * 128;
    const int wm = (wq & 1) * 64;
    const int wn = (wq >> 1) * 64;
    const int quad = lane >> 4;
    const int lm = lane & 15;
    const int z  = blockIdx.z;
    const int kstart = z * ksub;
    float* Cz = (z == 0) ? C : C2;

    const int lr4 = lane >> 4;
    const int lc  = lane & 15;

    f32x4 acc[4][4];
    #pragma unroll
    for (int i = 0; i < 4; i++)
        #pragma unroll
        for (int j = 0; j < 4; j++) {
            acc[i][j][0] = 0.f; acc[i][j][1] = 0.f;
            acc[i][j][2] = 0.f; acc[i][j][3] = 0.f;
        }

    for (int k0 = kstart; k0 < kstart + ksub; k0 += 128) {
        __syncthreads();
        #pragma unroll
        for (int i = 0; i < 4; ++i) {
            int seg = wave * 4 + i;          // 0..31, 4 rows each
            int r = seg * 4 + lr4;           // 0..127
            int ch = lc ^ (r & 7);           // global chunk for swizzled LDS
            gld_lds16(A + (size_t)(m0 + r) * K + k0 + ch * 8, &As[seg * 512]);
            gld_lds16(W + (size_t)(n0 + r) * K + k0 + ch * 8, &Bs[seg * 512]);
        }
        __syncthreads();
        #pragma unroll
        for (int kk = 0; kk < 2; ++kk) {
            bf16_8 af[4], bfr[4];
            #pragma unroll
            for (int t = 0; t < 4; ++t) {
                int ra = wm + t * 16 + lm;
                int ca = (kh * 8 + kk * 4 + quad) ^ (ra & 7);
                af[t]  = *(const bf16_8*)&As[ra * 128 + ca * 8];
                int rb = wn + t * 16 + lm;
                int cb = (kh * 8 + kk * 4 + quad) ^ (rb & 7);
                bfr[t] = *(const bf16_8*)&Bs[rb * 128 + cb * 8];
            }
            #pragma unroll
            for (int i = 0; i < 4; i++)
                #pragma unroll
                for (int j = 0; j < 4; j++)
                    acc[i][j] = __builtin_amdgcn_mfma_f32_16x16x32_bf16(
                        af[i], bfr[j], acc[i][j], 0, 0, 0);
        }
    }

    // ---- combine kh=1 -> kh=0 through the (dead) staging LDS ----
    __syncthreads();
    float* comb = (float*)smem;
    if (kh == 1) {
        #pragma unroll
        for (int i = 0; i < 4; i++)
            #pragma unroll
            for (int j = 0; j < 4; j++)
                *(f32x4*)&comb[wq * 4096 + (i * 4 + j) * 256 + lane * 4] =
                    acc[i][j];
    }
    __syncthreads();
    if (kh == 0) {
        float bvc[4];
        #pragma unroll
        for (int j = 0; j < 4; j++)
            bvc[j] = (z == 0) ? bias[n0 + wn + j * 16 + lm] : 0.f;
        #pragma unroll
        for (int i = 0; i < 4; i++)
            #pragma unroll
            for (int j = 0; j < 4; j++) {
                f32x4 v4 = *(const f32x4*)&comb[
                    wq * 4096 + (i * 4 + j) * 256 + lane * 4];
                int col = n0 + wn + j * 16 + lm;
                #pragma unroll
                for (int r = 0; r < 4; r++) {
                    int row = m0 + wm + i * 16 + quad * 4 + r;
                    Cz[(size_t)row * ldc + col] = acc[i][j][r] + v4[r] + bvc[j];
                }
            }
    }
}

// ---------------------------------------------------------------------------
// Merged QK + Vt GEMM v3 (round-12): 64x128 tiles -> 1536 blocks.
// Round-11 analysis: the 4-wave 128^2 version was GRID-limited — 768 blocks
// = 3 blocks/CU = 12 waves/CU cap (LDS 32KB and VGPR 116 both allowed more);
// occupancy 17%, latency-bound. Halving the M-tile doubles block count:
// 6 blocks/CU x 4 waves = 24 waves/CU. LDS 24 KB. Staging economy worsens
// 1.5x but qkvt runs at HBM 11% (L2-resident operands) — headroom.
// Per wave: 32m x 64n, acc[2][4] (32 VGPR — no bucket risk).
// blocks [0,1024):    qk16[4096,2048] = srcb @ [q_w;k_w]^T + qkb, Q cols xC2
// blocks [1024,1536): vtf [1024,4096] = vw16 @ srcb^T + v_b (row bias)
// Identity mapping (round-9: XCD remap regresses this latency-bound kernel).
// ---------------------------------------------------------------------------
__global__ __launch_bounds__(256) void gemm_qkvt_kernel(
    const unsigned short* __restrict__ srcb, const unsigned short* __restrict__ qkw,
    const unsigned short* __restrict__ vw16, const float* __restrict__ qkb,
    const float* __restrict__ v_b,
    unsigned short* __restrict__ qk16, unsigned short* __restrict__ vtf)
{
    const int bid = blockIdx.x;
    const unsigned short *A, *W;
    const float* bias;
    unsigned short* C;
    int m0, n0, ldc;
    bool qscale, rowbias;
    if (bid < 1024) {
        A = srcb; W = qkw; bias = qkb; C = qk16;
        n0 = (bid & 15) * 128; m0 = (bid >> 4) * 64;
        ldc = 2048; qscale = true; rowbias = false;
    } else {
        int b2 = bid - 1024;
        A = vw16; W = srcb; bias = v_b; C = vtf;
        n0 = (b2 & 31) * 128; m0 = (b2 >> 5) * 64;
        ldc = 4096; qscale = false; rowbias = true;
    }
    const int K = 1024;

    __shared__ __bf16 As[64][64];    // 8 KB
    __shared__ __bf16 Bs[128][64];   // 16 KB
    const int tid  = threadIdx.x;
    const int lane = tid & 63;
    const int wave = tid >> 6;
    const int lr8 = lane >> 3;
    const int gch = (lane & 7) ^ lr8;
    const int wm = (wave & 1) * 32;
    const int wn = (wave >> 1) * 64;
    const int quad = lane >> 4;
    const int lm = lane & 15;

    f32x4 acc[2][4];
    #pragma unroll
    for (int i = 0; i < 2; i++)
        #pragma unroll
        for (int j = 0; j < 4; j++) {
            acc[i][j][0] = 0.f; acc[i][j][1] = 0.f;
            acc[i][j][2] = 0.f; acc[i][j][3] = 0.f;
        }

    for (int k0 = 0; k0 < K; k0 += 64) {
        __syncthreads();
        #pragma unroll
        for (int i = 0; i < 2; i++) {         // A: 2 segments/wave (64 rows)
            int seg = wave * 2 + i;
            int r = seg * 8 + lr8;
            gld_lds16(A + (size_t)(m0 + r) * K + k0 + gch * 8, &As[seg * 8][0]);
        }
        #pragma unroll
        for (int i = 0; i < 4; i++) {         // B: 4 segments/wave (128 rows)
            int seg = wave * 4 + i;
            int r = seg * 8 + lr8;
            gld_lds16(W + (size_t)(n0 + r) * K + k0 + gch * 8, &Bs[seg * 8][0]);
        }
        __syncthreads();
        #pragma unroll
        for (int kh = 0; kh < 2; kh++) {
            bf16_8 af[2], bfr[4];
            #pragma unroll
            for (int t = 0; t < 2; t++) {
                int ch = (kh * 4 + quad) ^ (lm & 7);
                af[t] = *(const bf16_8*)&As[wm + t * 16 + lm][ch * 8];
            }
            #pragma unroll
            for (int j = 0; j < 4; j++) {
                int ch = (kh * 4 + quad) ^ (lm & 7);
                bfr[j] = *(const bf16_8*)&Bs[wn + j * 16 + lm][ch * 8];
            }
            #pragma unroll
            for (int i = 0; i < 2; i++)
                #pragma unroll
                for (int j = 0; j < 4; j++)
                    acc[i][j] = __builtin_amdgcn_mfma_f32_16x16x32_bf16(
                        af[i], bfr[j], acc[i][j], 0, 0, 0);
        }
    }

    float bvc[4];
    float brr[2][4];
    if (!rowbias) {
        #pragma unroll
        for (int j = 0; j < 4; j++) bvc[j] = bias[n0 + wn + j * 16 + lm];
    } else {
        #pragma unroll
        for (int i = 0; i < 2; i++) {
            float4 t4 = *(const float4*)&bias[m0 + wm + i * 16 + quad * 4];
            brr[i][0] = t4.x; brr[i][1] = t4.y; brr[i][2] = t4.z; brr[i][3] = t4.w;
        }
    }

    #pragma unroll
    for (int i = 0; i < 2; i++)
        #pragma unroll
        for (int j = 0; j < 4; j++) {
            int col = n0 + wn + j * 16 + lm;
            #pragma unroll
            for (int r = 0; r < 4; r++) {
                int row = m0 + wm + i * 16 + quad * 4 + r;
                float v = acc[i][j][r] + (rowbias ? brr[i][r] : bvc[j]);
                if (qscale && col < 1024) v *= ATT_C2;
                C[(size_t)row * ldc + col] = f2bf(v);
            }
        }
}

// ---------------------------------------------------------------------------
// FFN1 GEMM: hb[4096,4096] = relu(x1b[4096,1024] @ l1w[4096,1024]^T + l1_b).
// 256x128 tile, BK=64, LDS 48 KB, acc 4x8 per wave. 512 blocks = 2/CU exact.
// XCD remap kept (round-9 net win).
// ---------------------------------------------------------------------------
__global__ __launch_bounds__(256, 2) void gemm_ffn1_kernel(
    const unsigned short* __restrict__ A, const unsigned short* __restrict__ W,
    const float* __restrict__ bias, unsigned short* __restrict__ C)
{
    __shared__ __bf16 As[256][64];   // 32 KB
    __shared__ __bf16 Bs[128][64];   // 16 KB
    const int tid  = threadIdx.x;
    const int lane = tid & 63;
    const int wave = tid >> 6;
    // ---- XCD remap ----
    const int f   = blockIdx.x + (blockIdx.y << 5);  // 0..511
    const int xcd = f & 7;
    const int ib  = f >> 3;                          // 0..63
    const int mq  = (xcd >> 1) * 4 + (ib & 3);       // 0..15
    const int nq  = (xcd & 1) * 16 + (ib >> 2);      // 0..31
    const int m0 = mq * 256;
    const int n0 = nq * 128;
    const int lr8 = lane >> 3;
    const int gch = (lane & 7) ^ lr8;
    const int quad = lane >> 4;
    const int lm = lane & 15;

    f32x4 acc[4][8];
    #pragma unroll
    for (int i = 0; i < 4; i++)
        #pragma unroll
        for (int j = 0; j < 8; j++) {
            acc[i][j][0] = 0.f; acc[i][j][1] = 0.f;
            acc[i][j][2] = 0.f; acc[i][j][3] = 0.f;
        }

    for (int k0 = 0; k0 < 1024; k0 += 64) {
        __syncthreads();
        #pragma unroll
        for (int i = 0; i < 8; i++) {          // A: 8 segments/wave
            int seg = wave * 8 + i;
            int r = seg * 8 + lr8;
            gld_lds16(A + (size_t)(m0 + r) * 1024 + k0 + gch * 8, &As[seg * 8][0]);
        }
        #pragma unroll
        for (int i = 0; i < 4; i++) {          // B: 4 segments/wave
            int seg = wave * 4 + i;
            int r = seg * 8 + lr8;
            gld_lds16(W + (size_t)(n0 + r) * 1024 + k0 + gch * 8, &Bs[seg * 8][0]);
        }
        __syncthreads();
        #pragma unroll
        for (int kh = 0; kh < 2; kh++) {
            const int ch = (kh * 4 + quad) ^ (lm & 7);
            bf16_8 af[4], bfr[8];
            #pragma unroll
            for (int t = 0; t < 4; t++)
                af[t] = *(const bf16_8*)&As[wave * 64 + t * 16 + lm][ch * 8];
            #pragma unroll
            for (int j = 0; j < 8; j++)
                bfr[j] = *(const bf16_8*)&Bs[j * 16 + lm][ch * 8];
            #pragma unroll
            for (int i = 0; i < 4; i++)
                #pragma unroll
                for (int j = 0; j < 8; j++)
                    acc[i][j] = __builtin_amdgcn_mfma_f32_16x16x32_bf16(
                        af[i], bfr[j], acc[i][j], 0, 0, 0);
        }
    }

    float bv[8];
    #pragma unroll
    for (int j = 0; j < 8; j++) bv[j] = bias[n0 + j * 16 + lm];

    #pragma unroll
    for (int i = 0; i < 4; i++)
        #pragma unroll
        for (int j = 0; j < 8; j++) {
            int col = n0 + j * 16 + lm;
            #pragma unroll
            for (int r = 0; r < 4; r++) {
                int row = m0 + wave * 64 + i * 16 + quad * 4 + r;
                float v = fmaxf(acc[i][j][r] + bv[j], 0.f);
                C[(size_t)row * Ff + col] = f2bf(v);
            }
        }
}

// ---------------------------------------------------------------------------
// MFMA flash attention v5b (proven 50.1us, 56 VGPR, 16 waves/CU).
// Round-8 A/B: s_setprio null -> removed. Round-7: never 8 waves/SIMD here.
// Round-11 audit: the 4.19M SQ_LDS_BANK_CONFLICT is intrinsic b128
// multi-pass count (exactly 4/read across 5 different layouts), NOT fixable
// aliasing — K/V frag banks verified distinct per 8-lane group.
// Wave pairs (wq, wq+4) share one 32-t range; sh=wave>>2 picks s-blocks
// {0,1} or {2,3} of each 128-s tile. O/l partial combine through LDS.
// 512 thr, K/V double-buffered 64 KB, grid (16,32) = 2 blk/CU.
// ---------------------------------------------------------------------------
__global__ __launch_bounds__(512, 4) void attn_mfma_kernel(
    const unsigned short* __restrict__ qk,
    const unsigned short* __restrict__ vt,
    const unsigned* __restrict__ mbT,
    unsigned short* __restrict__ out)
{
    __shared__ __align__(16) char smem[65536];
    __bf16* KsP = (__bf16*)smem;             // [2][8192] = 2 x 16 KB
    __bf16* VtP = (__bf16*)(smem + 32768);   // [2][8192] = 2 x 16 KB

    const int tid  = threadIdx.x;
    const int lane = tid & 63;
    const int wave = tid >> 6;           // 0..7
    const int l31  = lane & 31;
    const int hi   = lane >> 5;
    const int x7   = l31 & 7;
    const int bh = blockIdx.y;
    const int b = bh >> 4, h = bh & 15;
    // wave-uniform (SGPR) wave decomposition: wq = t-range, sh = s-half
    const int wvu = __builtin_amdgcn_readfirstlane(wave);
    const int wq  = wvu & 3;
    const int sh  = wvu >> 2;
    const int tw = blockIdx.x * 128 + wq * 32;
    const unsigned* mrow = mbT + (size_t)(blockIdx.x * 4 + wq) * 2048;

    // Q B-frags: B[k=hi*8+j][col=t=l31], 4 dsteps of 16 covering d=0..63
    bf16_8 qf[4];
    #pragma unroll
    for (int ds4 = 0; ds4 < 4; ++ds4)
        qf[ds4] = *(const bf16_8*)(qk +
            (size_t)(b * Tt + tw + l31) * 2048 + h * DHd + ds4 * 16 + hi * 8);

    f32x16 oacc[2];
    f32x16 ol;
    f32x16 z16;
    #pragma unroll
    for (int r = 0; r < 16; ++r) {
        oacc[0][r] = 0.f; oacc[1][r] = 0.f; ol[r] = 0.f; z16[r] = 0.f;
    }
    bf16_8 vone;
    {
        __bf16 one = (__bf16)1.0f;
        #pragma unroll
        for (int j = 0; j < 8; ++j) vone[j] = one;
    }

    const int krow8 = lane >> 3;
    const int kj    = (lane & 7) ^ krow8;    // K staging swizzle
    const int vr4   = lane >> 4;

    auto STAGE = [&](int nb, int s0) {
        #pragma unroll
        for (int i = 0; i < 2; ++i) {
            int ci = wave * 2 + i;           // 0..15
            {
                int r = 8 * ci + krow8;
                const unsigned short* g = qk +
                    (size_t)(b * Tt + s0 + r) * 2048 + 1024 + h * DHd + kj * 8;
                gld_lds16(g, &KsP[nb * 8192 + ci * 512]);
            }
            {
                int d = 4 * ci + vr4;
                int jj = (lane & 15) ^ (d & 7);
                const unsigned short* g = vt +
                    (size_t)(h * DHd + d) * 4096 + b * Tt + s0 + jj * 8;
                gld_lds16(g, &VtP[nb * 8192 + ci * 512]);
            }
        }
    };

    STAGE(0, 0);

    for (int st = 0; st < 16; ++st) {
        const int cb = st & 1;
        const int s0 = st * 128;
        __syncthreads();                     // buf[cb] staged; buf[cb^1] free

        if (st < 15) STAGE(cb ^ 1, s0 + 128);

        #pragma unroll
        for (int sbl = 0; sbl < 2; ++sbl) {
            const int sb = sh * 2 + sbl;     // this wave's s-block (uniform)
            // keep-bit words for s = s0+sb*32 .. +31 (scalar pipe)
            u32x8s ma, mbw, mc, md;
            sload32(mrow + s0 + sb * 32, ma, mbw, mc, md);

            // ---- S^T: 32 s x 32 t, K streamed from LDS, Q in regs ----
            f32x16 sacc = z16;
            #pragma unroll
            for (int ds4 = 0; ds4 < 4; ++ds4) {
                bf16_8 kf = *(const bf16_8*)&KsP[cb * 8192 +
                    (sb * 32 + l31) * 64 + (((ds4 * 2 + hi) ^ x7) * 8)];
                sacc = __builtin_amdgcn_mfma_f32_32x32x16_bf16(
                    kf, qf[ds4], sacc, 0, 0, 0);
            }
            // ---- exp2 + SGPR-mask select (1 cndmask/elem) ----
            float p[16];
            #pragma unroll
            for (int g = 0; g < 4; ++g) {
                u32x8s vv = (g == 0) ? ma : (g == 1) ? mbw : (g == 2) ? mc : md;
                #pragma unroll
                for (int m = 0; m < 4; ++m) {
                    const int reg = g * 4 + m;
                    unsigned long long keep =
                        ((unsigned long long)vv[m + 4] << 32) |
                        (unsigned long long)vv[m];
                    float e = __builtin_amdgcn_exp2f(sacc[reg]);
                    p[reg] = selkeep(e, keep);
                }
            }
            // ---- in-register repack to PV A-frags (T12) ----
            unsigned u[4], v[4];
            #pragma unroll
            for (int g = 0; g < 4; ++g) {
                u[g] = __builtin_bit_cast(unsigned, pkbf(p[g * 4 + 0], p[g * 4 + 1]));
                v[g] = __builtin_bit_cast(unsigned, pkbf(p[g * 4 + 2], p[g * 4 + 3]));
            }
            plswap32(u[0], u[1]); plswap32(v[0], v[1]);   // kstep0: s 0..15
            plswap32(u[2], u[3]); plswap32(v[2], v[3]);   // kstep1: s 16..31
            u32x4 w0; w0[0] = u[0]; w0[1] = v[0]; w0[2] = u[1]; w0[3] = v[1];
            u32x4 w1; w1[0] = u[2]; w1[1] = v[2]; w1[2] = u[3]; w1[3] = v[3];
            bf16_8 pa0 = __builtin_bit_cast(bf16_8, w0);
            bf16_8 pa1 = __builtin_bit_cast(bf16_8, w1);
            // ---- PV + l: O[t][d] += P V, l[t] += P·1 ----
            #pragma unroll
            for (int kst = 0; kst < 2; ++kst) {
                bf16_8 pa = kst ? pa1 : pa0;
                #pragma unroll
                for (int dblk = 0; dblk < 2; ++dblk) {
                    int cpos = (sb * 4 + kst * 2 + hi) ^ x7;
                    bf16_8 vf = *(const bf16_8*)&VtP[cb * 8192 +
                        ((dblk * 32 + l31) * 16 + cpos) * 8];
                    oacc[dblk] = __builtin_amdgcn_mfma_f32_32x32x16_bf16(
                        pa, vf, oacc[dblk], 0, 0, 0);
                }
                ol = __builtin_amdgcn_mfma_f32_32x32x16_bf16(
                    pa, vone, ol, 0, 0, 0);
            }
        }
    }

    // ---- combine wave-pair partials (sh=1 -> sh=0) through LDS ----
    // layout: comb[wq*3072 + piece*256 + lane*4], piece 0..7 = oacc, 8..11 = ol
    __syncthreads();                         // all compute done; K/V dead
    float* comb = (float*)smem;              // 48 KB of the 64 KB
    if (sh == 1) {
        #pragma unroll
        for (int dblk = 0; dblk < 2; ++dblk)
            #pragma unroll
            for (int q = 0; q < 4; ++q) {
                float4 v4 = { oacc[dblk][q * 4 + 0], oacc[dblk][q * 4 + 1],
                              oacc[dblk][q * 4 + 2], oacc[dblk][q * 4 + 3] };
                *(float4*)&comb[wq * 3072 + (dblk * 4 + q) * 256 + lane * 4] = v4;
            }
        #pragma unroll
        for (int q = 0; q < 4; ++q) {
            float4 v4 = { ol[q * 4 + 0], ol[q * 4 + 1],
                          ol[q * 4 + 2], ol[q * 4 + 3] };
            *(float4*)&comb[wq * 3072 + (8 + q) * 256 + lane * 4] = v4;
        }
    }
    __syncthreads();
    if (sh == 0) {
        #pragma unroll
        for (int dblk = 0; dblk < 2; ++dblk)
            #pragma unroll
            for (int q = 0; q < 4; ++q) {
                float4 v4 = *(const float4*)&comb[
                    wq * 3072 + (dblk * 4 + q) * 256 + lane * 4];
                oacc[dblk][q * 4 + 0] += v4.x; oacc[dblk][q * 4 + 1] += v4.y;
                oacc[dblk][q * 4 + 2] += v4.z; oacc[dblk][q * 4 + 3] += v4.w;
            }
        #pragma unroll
        for (int q = 0; q < 4; ++q) {
            float4 v4 = *(const float4*)&comb[
                wq * 3072 + (8 + q) * 256 + lane * 4];
            ol[q * 4 + 0] += v4.x; ol[q * 4 + 1] += v4.y;
            ol[q * 4 + 2] += v4.z; ol[q * 4 + 3] += v4.w;
        }
        // ---- epilogue: O / l (all-masked row: l=0 -> 0), store bf16 ----
        #pragma unroll
        for (int g = 0; g < 4; ++g)
            #pragma unroll
            for (int m = 0; m < 4; ++m) {
                const int reg = g * 4 + m;
                const int tr = m + 8 * g + 4 * hi;      // row within 32-block
                float l = ol[reg];
                float inv = (l > 0.f) ? 1.f / l : 0.f;
                int row = b * Tt + tw + tr;
                #pragma unroll
                for (int dblk = 0; dblk < 2; ++dblk)
                    out[(size_t)row * Dm + h * DHd + dblk * 32 + l31] =
                        f2bf(oacc[dblk][reg] * inv);
            }
    }
}

// ---------------------------------------------------------------------------
// out = LayerNorm(base + alpha*(d0[+d1]))*scale + bias.
// BASEBF: base is bf16. OUTF32 -> out fp32; OUTBF -> out_bf bf16.
// ---------------------------------------------------------------------------
template<int NPARTS, int BASEBF, int OUTF32, int OUTBF>
__global__ __launch_bounds__(256) void residual_ln_kernel(
    const void* __restrict__ base, const float* __restrict__ d0,
    const float* __restrict__ d1,
    const float* __restrict__ alpha_p, const float* __restrict__ scale,
    const float* __restrict__ bias, float* __restrict__ out,
    unsigned short* __restrict__ out_bf)
{
    const int row = blockIdx.x;
    const int tid = threadIdx.x;
    const float alpha = alpha_p[0];
    float4 xb;
    if (BASEBF) {
        bf16x4 bb = ((const bf16x4*)((const unsigned short*)base + (size_t)row * Dm))[tid];
        xb.x = (float)bb[0]; xb.y = (float)bb[1]; xb.z = (float)bb[2]; xb.w = (float)bb[3];
    } else {
        xb = ((const float4*)((const float*)base + (size_t)row * Dm))[tid];
    }
    float4 xd = ((const float4*)(d0 + (size_t)row * Dm))[tid];
    if (NPARTS == 2) {
        float4 x2 = ((const float4*)(d1 + (size_t)row * Dm))[tid];
        xd.x += x2.x; xd.y += x2.y; xd.z += x2.z; xd.w += x2.w;
    }
    float4 x;
    x.x = xb.x + alpha * xd.x;
    x.y = xb.y + alpha * xd.y;
    x.z = xb.z + alpha * xd.z;
    x.w = xb.w + alpha * xd.w;
    float s  = x.x + x.y + x.z + x.w;
    float sq = x.x*x.x + x.y*x.y + x.z*x.z + x.w*x.w;
    #pragma unroll
    for (int off = 32; off > 0; off >>= 1) {
        s  += __shfl_down(s, off, 64);
        sq += __shfl_down(sq, off, 64);
    }
    __shared__ float red[8];
    const int w = tid >> 6;
    if ((tid & 63) == 0) { red[w] = s; red[4 + w] = sq; }
    __syncthreads();
    s  = red[0] + red[1] + red[2] + red[3];
    sq = red[4] + red[5] + red[6] + red[7];
    const float mu  = s * (1.f / Dm);
    const float var = sq * (1.f / Dm) - mu * mu;
    const float r   = rsqrtf(var + 1e-5f);
    float4 sc = ((const float4*)scale)[tid];
    float4 bi = ((const float4*)bias)[tid];
    float4 o;
    o.x = (x.x - mu) * r * sc.x + bi.x;
    o.y = (x.y - mu) * r * sc.y + bi.y;
    o.z = (x.z - mu) * r * sc.z + bi.z;
    o.w = (x.w - mu) * r * sc.w + bi.w;
    if (OUTF32)
        ((float4*)(out + (size_t)row * Dm))[tid] = o;
    if (OUTBF)
        ((bf16x4*)(out_bf + (size_t)row * Dm))[tid] = pkbf4(o.x, o.y, o.z, o.w);
}

// ---------------------------------------------------------------------------
extern "C" void kernel_launch(void* const* d_in, const int* in_sizes, int n_in,
                              void* d_out, int out_size, void* d_ws, size_t ws_size,
                              hipStream_t stream)
{
    (void)in_sizes; (void)n_in; (void)out_size; (void)ws_size;
    const float* src  = (const float*)d_in[0];
    const int*   mask = (const int*)  d_in[1];
    const float* q_w  = (const float*)d_in[2];
    const float* q_b  = (const float*)d_in[3];
    const float* k_w  = (const float*)d_in[4];
    const float* k_b  = (const float*)d_in[5];
    const float* v_w  = (const float*)d_in[6];
    const float* v_b  = (const float*)d_in[7];
    const float* o_w  = (const float*)d_in[8];
    const float* o_b  = (const float*)d_in[9];
    const float* l1_w = (const float*)d_in[10];
    const float* l1_b = (const float*)d_in[11];
    const float* l2_w = (const float*)d_in[12];
    const float* l2_b = (const float*)d_in[13];
    const float* n1_s = (const float*)d_in[14];
    const float* n1_b = (const float*)d_in[15];
    const float* n2_s = (const float*)d_in[16];
    const float* n2_b = (const float*)d_in[17];
    const float* a_attn = (const float*)d_in[18];
    const float* a_ff   = (const float*)d_in[19];

    // ---- workspace layout (96 MB), lifetimes annotated ----
    const size_t MB = 1024 * 1024;
    char* w = (char*)d_ws;
    unsigned short* qkw  = (unsigned short*)(w + 0);        // [ 0, 4)   -> qkvt
    unsigned short* vw16 = (unsigned short*)(w + 4  * MB);  // [ 4, 6)   -> qkvt
    unsigned short* ow   = (unsigned short*)(w + 6  * MB);  // [ 6, 8)   -> O gemm
    unsigned short* l1w  = (unsigned short*)(w + 8  * MB);  // [ 8,16)   -> FFN1
    unsigned short* l2w  = (unsigned short*)(w + 16 * MB);  // [16,24)   -> FFN2
    unsigned short* srcb = (unsigned short*)(w + 24 * MB);  // [24,32)   -> qkvt
    unsigned short* qk16 = (unsigned short*)(w + 32 * MB);  // [32,48)   -> attn
    unsigned short* vtf  = (unsigned short*)(w + 48 * MB);  // [48,56)   -> attn
    unsigned*       mbT  = (unsigned*)      (w + 56 * MB);            // 512 KB
    float*          qkb  = (float*)         (w + 56 * MB + 524288);   // 8 KB
    // post-attention reuse:
    unsigned short* atb  = (unsigned short*)(w + 24 * MB);  // [24,32)   -> O gemm (srcb dead)
    float*          o0   = (float*)         (w + 58 * MB);  // [58,74)   -> LN1
    float*          o1   = (float*)         (w + 74 * MB);  // [74,90)   -> LN1
    unsigned short* x1b  = (unsigned short*)(w + 48 * MB);  // [48,56)   -> FFN1+LN2 (vtf dead)
    unsigned short* hb   = (unsigned short*)(w + 58 * MB);  // [58,90)   -> FFN2 (o0/o1 dead)
    float*          fp0  = (float*)         (w + 0);        // [ 0,16)   -> LN2 (qkw/vw16/ow dead)
    float*          fp1  = (float*)         (w + 32 * MB);  // [32,48)   -> LN2 (qk16 dead)

    const int MR = Bb * Tt;   // 4096
    dim3 blk(256);

    // 1) conversions + mask pack + bias concat
    preprocess_kernel<<<dim3(16904), blk, 0, stream>>>(
        q_w, k_w, v_w, o_w, l1_w, l2_w, src, mask, q_b, k_b,
        qkw, vw16, ow, l1w, l2w, srcb, mbT, qkb);
    // 2) merged QK + Vt GEMMs: 64x128 tiles, 1536 blocks (6/CU)
    gemm_qkvt_kernel<<<dim3(1536), blk, 0, stream>>>(
        srcb, qkw, vw16, qkb, v_b, qk16, vtf);
    // 3) MFMA flash attention -> atb bf16 (v5b, proven)
    attn_mfma_kernel<<<dim3(16, 32), dim3(512), 0, stream>>>(qk16, vtf, mbT, atb);
    // 4) O projection: splitk8 + XCD remap, z=2 -> fp32 partials
    gemm_splitk8_kernel<<<dim3(8, 32, 2), dim3(512), 0, stream>>>(
        atb, ow, o_b, o0, o1, Dm, Dm, 512);
    // 5) LN1 (sums O partials) -> x1b bf16 only
    residual_ln_kernel<2, 0, 0, 1><<<dim3(MR), blk, 0, stream>>>(
        src, o0, o1, a_attn, n1_s, n1_b, nullptr, x1b);
    // 6) FFN1 + ReLU -> bf16 hidden, 256x128 tile + XCD remap
    gemm_ffn1_kernel<<<dim3(32, 16), blk, 0, stream>>>(x1b, l1w, l1_b, hb);
    // 7) FFN2: splitk8 + XCD remap, z=2 -> fp32 partials
    gemm_splitk8_kernel<<<dim3(8, 32, 2), dim3(512), 0, stream>>>(
        hb, l2w, l2_b, fp0, fp1, Ff, Dm, 2048);
    // 8) LN2 (bf16 base x1b; sums FFN2 partials) -> final fp32 output
    residual_ln_kernel<2, 1, 1, 0><<<dim3(MR), blk, 0, stream>>>(
        x1b, fp0, fp1, a_ff, n2_s, n2_b, (float*)d_out, nullptr);
}